// Round 17
// baseline (6008.450 us; speedup 1.0000x reference)
//
#include <hip/hip_runtime.h>
#include <stdint.h>

#define TSN 400
#define NB 16
#define HENC 512
#define HD2 1024
#define G3E 1536
#define G3D 3072
#define EMBD 300
#define AEMB 32
#define NV 50000
#define NEXT 50100
#define NVP 50176
#define NTT 32
#define NEG_INF (-1.0e12f)

typedef __attribute__((ext_vector_type(8))) short bf16x8;
typedef __attribute__((ext_vector_type(4))) float f32x4;

struct CJob { const float4* s; ushort* d; long n8; };
struct CJobs { CJob j[12]; int nj; };

__device__ __forceinline__ ushort f2bf(float f) {
  unsigned u = __float_as_uint(f);
  unsigned r = (u + 0x7fffu + ((u >> 16) & 1u)) >> 16;
  return (ushort)r;
}
__device__ __forceinline__ float bf2f(ushort h) {
  return __uint_as_float((unsigned)h << 16);
}
__device__ __forceinline__ unsigned agat_ld(const unsigned* p) {
  return __hip_atomic_load(p, __ATOMIC_RELAXED, __HIP_MEMORY_SCOPE_AGENT);
}
__device__ __forceinline__ void agat_st(unsigned* p, unsigned v) {
  __hip_atomic_store(p, v, __ATOMIC_RELAXED, __HIP_MEMORY_SCOPE_AGENT);
}
__device__ __forceinline__ unsigned long long agat_ld64(const unsigned long long* p) {
  return __hip_atomic_load(p, __ATOMIC_RELAXED, __HIP_MEMORY_SCOPE_AGENT);
}

// ---------------- embeddings -> bf16, padded K=384 ----------------
__global__ __launch_bounds__(256) void k_embed_bf(
    const float* __restrict__ enc_emb, const float* __restrict__ ans_emb,
    const int* __restrict__ input_s, const int* __restrict__ input_a,
    ushort* __restrict__ X0)
{
  long i = (long)blockIdx.x*256 + threadIdx.x;
  if (i >= (long)TSN*NB*384) return;
  int c = (int)(i % 384);
  long r = i / 384;
  int b = (int)(r % NB);
  int t = (int)(r / NB);
  float v = 0.f;
  if (c < EMBD) v = enc_emb[(long)input_s[b*TSN + t]*EMBD + c];
  else if (c < 332) v = ans_emb[(long)input_a[b*TSN + t]*AEMB + (c - EMBD)];
  X0[i] = f2bf(v);
}

// ---------------- decoder emb -> bf16, padded K=320 ----------------
__global__ __launch_bounds__(256) void k_embq_bf(
    const float* __restrict__ dec_emb, const int* __restrict__ input_q,
    ushort* __restrict__ EQ)
{
  long i = (long)blockIdx.x*256 + threadIdx.x;
  if (i >= (long)NTT*NB*320) return;
  int c = (int)(i % 320);
  long r = i / 320;
  int b = (int)(r % NB);
  int s = (int)(r / NB);
  EQ[i] = (c < EMBD) ? f2bf(dec_emb[(long)input_q[b*33 + s]*EMBD + c]) : (ushort)0;
}

// ---------------- weight cast with pad (strided / padded cases) ----------------
__global__ __launch_bounds__(256) void k_castw(
    const float* __restrict__ src, ushort* __restrict__ dst,
    int Nsrc, long total, int Ksrc, int Kdst, int ldsrc, int coloff)
{
  long i = (long)blockIdx.x*256 + threadIdx.x;
  if (i >= total) return;
  int k = (int)(i % Kdst);
  long n = i / Kdst;
  float v = (n < Nsrc && k < Ksrc) ? src[n*ldsrc + coloff + k] : 0.f;
  dst[i] = f2bf(v);
}

// ---------------- vectorized contiguous cast ----------------
__global__ __launch_bounds__(256) void k_cast8(
    const float4* __restrict__ s, ushort* __restrict__ d, long n8)
{
  long i = (long)blockIdx.x*256 + threadIdx.x;
  if (i >= n8) return;
  float4 v0 = s[2*i], v1 = s[2*i + 1];
  union { ushort u[8]; bf16x8 h; } c;
  c.u[0] = f2bf(v0.x); c.u[1] = f2bf(v0.y); c.u[2] = f2bf(v0.z); c.u[3] = f2bf(v0.w);
  c.u[4] = f2bf(v1.x); c.u[5] = f2bf(v1.y); c.u[6] = f2bf(v1.z); c.u[7] = f2bf(v1.w);
  *(bf16x8*)&d[i*8] = c.h;
}

// ---------------- multi-job contiguous cast (one launch) ----------------
__global__ __launch_bounds__(256) void k_cast8_multi(CJobs jobs)
{
  const long stride = (long)gridDim.x*256;
  for (int ji = 0; ji < jobs.nj; ++ji) {
    const float4* s = jobs.j[ji].s;
    ushort* d = jobs.j[ji].d;
    const long n8 = jobs.j[ji].n8;
    for (long i = (long)blockIdx.x*256 + threadIdx.x; i < n8; i += stride) {
      float4 v0 = s[2*i], v1 = s[2*i + 1];
      union { ushort u[8]; bf16x8 h; } c;
      c.u[0] = f2bf(v0.x); c.u[1] = f2bf(v0.y); c.u[2] = f2bf(v0.z); c.u[3] = f2bf(v0.w);
      c.u[4] = f2bf(v1.x); c.u[5] = f2bf(v1.y); c.u[6] = f2bf(v1.z); c.u[7] = f2bf(v1.w);
      *(bf16x8*)&d[i*8] = c.h;
    }
  }
}

// ---------------- plain cast fp32 -> bf16 ----------------
__global__ __launch_bounds__(256) void k_cast(
    const float* __restrict__ s, ushort* __restrict__ d, long n)
{
  long i = (long)blockIdx.x*256 + threadIdx.x;
  if (i >= n) return;
  d[i] = f2bf(s[i]);
}

// ---------------- bf16 batched transpose with K-pad: out[b][c][r(448)] ----------------
__global__ __launch_bounds__(256) void k_transpose_hh(
    const ushort* __restrict__ in, ushort* __restrict__ out, int ldin)
{
  __shared__ ushort tb[32][33];
  int b = blockIdx.z;
  int r0 = blockIdx.x*32, c0 = blockIdx.y*32;
  int tx = threadIdx.x & 31, ty = threadIdx.x >> 5;
  #pragma unroll
  for (int i = 0; i < 32; i += 8) {
    int r = r0 + ty + i, c = c0 + tx;
    tb[ty+i][tx] = (r < TSN) ? in[((long)b*TSN + r)*ldin + c] : (ushort)0;
  }
  __syncthreads();
  #pragma unroll
  for (int i = 0; i < 32; i += 8) {
    int c = c0 + ty + i, r = r0 + tx;
    out[((long)b*1024 + c)*448 + r] = tb[tx][ty+i];
  }
}

// ---------------- MFMA GEMM 64x64 (fp32 C optional; bf16 C2 optional) ----------------
__global__ __launch_bounds__(256) void k_mfma_nt(
    const ushort* __restrict__ Ab, const ushort* __restrict__ Wb,
    const float* __restrict__ bias, float* __restrict__ Cb, ushort* __restrict__ C2b,
    int M, int N, int K, int lda, int ldw, int ldc,
    long sA, long sW, long sC, long sBias, int accum, int act)
{
  __shared__ ushort As[64][72];
  __shared__ ushort Ws[64][72];
  const ushort* A = Ab + (long)blockIdx.z * sA;
  const ushort* W = Wb + (long)blockIdx.z * sW;
  float* C = Cb ? Cb + (long)blockIdx.z * sC : nullptr;
  const float* bi = bias ? bias + (long)blockIdx.z * sBias : nullptr;
  const int m0 = blockIdx.x*64, n0 = blockIdx.y*64;
  const int tid = threadIdx.x;
  const int wave = tid >> 6, lane = tid & 63;
  const int wm = wave >> 1, wn = wave & 1;
  const int lr = lane & 15, kg = lane >> 4;
  f32x4 acc[2][2] = {};
  for (int k0 = 0; k0 < K; k0 += 64) {
    __syncthreads();
    #pragma unroll
    for (int it = 0; it < 2; ++it) {
      int sidx = tid + it*256;
      int r = sidx >> 3, c = (sidx & 7)*8;
      bf16x8 av = {};
      bf16x8 wv = {};
      if (m0 + r < M) av = *(const bf16x8*)&A[(long)(m0+r)*lda + k0 + c];
      if (n0 + r < N) wv = *(const bf16x8*)&W[(long)(n0+r)*ldw + k0 + c];
      *(bf16x8*)&As[r][c] = av;
      *(bf16x8*)&Ws[r][c] = wv;
    }
    __syncthreads();
    #pragma unroll
    for (int kk = 0; kk < 2; ++kk) {
      bf16x8 af[2], bf[2];
      #pragma unroll
      for (int mt = 0; mt < 2; ++mt)
        af[mt] = *(const bf16x8*)&As[wm*32 + mt*16 + lr][kk*32 + kg*8];
      #pragma unroll
      for (int nt = 0; nt < 2; ++nt)
        bf[nt] = *(const bf16x8*)&Ws[wn*32 + nt*16 + lr][kk*32 + kg*8];
      #pragma unroll
      for (int mt = 0; mt < 2; ++mt)
        #pragma unroll
        for (int nt = 0; nt < 2; ++nt)
          acc[mt][nt] = __builtin_amdgcn_mfma_f32_16x16x32_bf16(af[mt], bf[nt], acc[mt][nt], 0, 0, 0);
    }
  }
  #pragma unroll
  for (int mt = 0; mt < 2; ++mt) {
    #pragma unroll
    for (int r = 0; r < 4; ++r) {
      int m = m0 + wm*32 + mt*16 + kg*4 + r;
      if (m >= M) continue;
      #pragma unroll
      for (int nt = 0; nt < 2; ++nt) {
        int n = n0 + wn*32 + nt*16 + lr;
        if (n >= N) continue;
        float v = acc[mt][nt][r];
        if (accum && C) v += C[(long)m*ldc + n];
        if (bi)    v += bi[n];
        if (act == 1) v = tanhf(v);
        else if (act == 2) v = 1.f/(1.f + expf(-v));
        if (C) C[(long)m*ldc + n] = v;
        if (C2b) C2b[(long)blockIdx.z*sC + (long)m*ldc + n] = f2bf(v);
      }
    }
  }
}

// ---------------- MFMA GEMM 128x128 (guard-free, bias optional, bf16 out) ----------------
__global__ __launch_bounds__(256) void k_mfma128(
    const ushort* __restrict__ Ab, const ushort* __restrict__ Wb,
    const float* __restrict__ bias, ushort* __restrict__ C2b,
    int K, int lda, int ldw, int ldc,
    long sA, long sW, long sC, long sBias)
{
  __shared__ ushort As[128][72];
  __shared__ ushort Ws[128][72];
  const ushort* A = Ab + (long)blockIdx.z * sA;
  const ushort* W = Wb + (long)blockIdx.z * sW;
  ushort* C2 = C2b + (long)blockIdx.z * sC;
  const float* bi = bias ? bias + (long)blockIdx.z * sBias : nullptr;
  const int m0 = blockIdx.x*128, n0 = blockIdx.y*128;
  const int tid = threadIdx.x;
  const int wave = tid >> 6, lane = tid & 63;
  const int wm = wave >> 1, wn = wave & 1;
  const int lr = lane & 15, kg = lane >> 4;
  f32x4 acc[4][4] = {};
  for (int k0 = 0; k0 < K; k0 += 64) {
    __syncthreads();
    #pragma unroll
    for (int it = 0; it < 4; ++it) {
      int idx = it*256 + tid;
      int r = idx >> 3, c = (idx & 7)*8;
      *(bf16x8*)&As[r][c] = *(const bf16x8*)&A[(long)(m0+r)*lda + k0 + c];
      *(bf16x8*)&Ws[r][c] = *(const bf16x8*)&W[(long)(n0+r)*ldw + k0 + c];
    }
    __syncthreads();
    #pragma unroll
    for (int kk = 0; kk < 2; ++kk) {
      bf16x8 af[4], bfv[4];
      #pragma unroll
      for (int mt = 0; mt < 4; ++mt)
        af[mt] = *(const bf16x8*)&As[wm*64 + mt*16 + lr][kk*32 + kg*8];
      #pragma unroll
      for (int nt = 0; nt < 4; ++nt)
        bfv[nt] = *(const bf16x8*)&Ws[wn*64 + nt*16 + lr][kk*32 + kg*8];
      #pragma unroll
      for (int mt = 0; mt < 4; ++mt)
        #pragma unroll
        for (int nt = 0; nt < 4; ++nt)
          acc[mt][nt] = __builtin_amdgcn_mfma_f32_16x16x32_bf16(af[mt], bfv[nt], acc[mt][nt], 0, 0, 0);
    }
  }
  #pragma unroll
  for (int mt = 0; mt < 4; ++mt) {
    #pragma unroll
    for (int r = 0; r < 4; ++r) {
      int m = m0 + wm*64 + mt*16 + kg*4 + r;
      #pragma unroll
      for (int nt = 0; nt < 4; ++nt) {
        int n = n0 + wn*64 + nt*16 + lr;
        float v = acc[mt][nt][r];
        if (bi) v += bi[n];
        C2[(long)m*ldc + n] = f2bf(v);
      }
    }
  }
}

// ---------------- persistent MFMA bidirectional GRU scan v6 (proven; ldY param) ----------------
__global__ __launch_bounds__(256, 1) void k_scan_mfma(
    const ushort* __restrict__ GXf, const ushort* __restrict__ GXb,
    const ushort* __restrict__ Whb,
    const float* __restrict__ bh,
    ushort* __restrict__ Ybf, int bmajor, int ldY,
    float* __restrict__ hfin,
    ushort* __restrict__ hpp,
    int* __restrict__ slots)
{
  const int bid = blockIdx.x;
  const int tid = threadIdx.x;
  const int wg = bid*4 + (tid >> 6);
  const int lane = tid & 63;
  const int lr = lane & 15, kg = lane >> 4;
  const int dir = wg >> 5, jt = wg & 31;
  const int j = jt*16 + lr;
  __shared__ ushort hsm[16][520];
  const ushort* Wp0 = Whb + ((long)(dir*G3E + j)        << 9) + kg*8;
  const ushort* Wp1 = Whb + ((long)(dir*G3E + 512 + j)  << 9) + kg*8;
  const ushort* Wp2 = Whb + ((long)(dir*G3E + 1024 + j) << 9) + kg*8;
  bf16x8 W0[16], W1[16], W2[16];
  #pragma unroll
  for (int i = 0; i < 16; ++i) {
    W0[i] = *(const bf16x8*)(Wp0 + i*32);
    W1[i] = *(const bf16x8*)(Wp1 + i*32);
    W2[i] = *(const bf16x8*)(Wp2 + i*32);
  }
  const float bh0 = bh[dir*G3E + j];
  const float bh1 = bh[dir*G3E + 512 + j];
  const float bh2 = bh[dir*G3E + 1024 + j];
  const ushort* GX = dir ? GXb : GXf;
  unsigned* hppu = (unsigned*)hpp;
  int* myslot = slots + dir*256 + (bid & 7)*32;
  int* dslots = slots + dir*256;
  float hreg[4] = {0.f, 0.f, 0.f, 0.f};
  float g0[4], g1[4], g2[4];
  {
    const int t0 = dir ? (TSN - 1) : 0;
    const ushort* gxp = GX + (long)t0*NB*G3E + j;
    #pragma unroll
    for (int r = 0; r < 4; ++r) {
      const ushort* g = gxp + (long)(kg*4 + r)*G3E;
      g0[r] = bf2f(g[0]); g1[r] = bf2f(g[512]); g2[r] = bf2f(g[1024]);
    }
  }
  for (int s = 0; s < TSN; ++s) {
    const int cur = s & 1;
    {
      const unsigned long long* hin =
          (const unsigned long long*)hppu + (cur*2 + dir)*2048;
      unsigned long long vqw[8];
      #pragma unroll
      for (int i = 0; i < 8; ++i) vqw[i] = agat_ld64(hin + i*256 + tid);
      #pragma unroll
      for (int i = 0; i < 8; ++i) {
        int d0 = 2*(i*256 + tid);
        *(unsigned long long*)&hsm[d0 >> 8][(d0 & 255)*2] = vqw[i];
      }
    }
    __syncthreads();
    f32x4 a0 = {}, a1 = {}, a2 = {};
    #pragma unroll
    for (int i = 0; i < 16; ++i) {
      bf16x8 hf = *(const bf16x8*)&hsm[lr][kg*8 + i*32];
      a0 = __builtin_amdgcn_mfma_f32_16x16x32_bf16(hf, W0[i], a0, 0, 0, 0);
      a1 = __builtin_amdgcn_mfma_f32_16x16x32_bf16(hf, W1[i], a1, 0, 0, 0);
      a2 = __builtin_amdgcn_mfma_f32_16x16x32_bf16(hf, W2[i], a2, 0, 0, 0);
    }
    const int t = dir ? (TSN - 1 - s) : s;
    const int obase = ((cur^1)*2 + dir)*16*512;
    float hsave[4];
    #pragma unroll
    for (int r = 0; r < 4; ++r) {
      int b = kg*4 + r;
      float rr = 1.f/(1.f + expf(-(g0[r] + a0[r] + bh0)));
      float zz = 1.f/(1.f + expf(-(g1[r] + a1[r] + bh1)));
      float nn = tanhf(g2[r] + rr*(a2[r] + bh2));
      float hn = (1.f - zz)*nn + zz*hreg[r];
      hreg[r] = hn;
      hsave[r] = hn;
      unsigned hv = f2bf(hn);
      unsigned pv = (unsigned)__shfl_xor((int)hv, 1);
      if ((lr & 1) == 0)
        agat_st(hppu + ((obase + b*512 + j) >> 1), hv | (pv << 16));
    }
    if (s + 1 < TSN) {
      asm volatile("s_waitcnt vmcnt(0)" ::: "memory");
      __syncthreads();
      if (tid == 0)
        agat_st((unsigned*)myslot, (unsigned)(s + 1));
      {
        const int tn = dir ? (TSN - 2 - s) : (s + 1);
        const ushort* gxp = GX + (long)tn*NB*G3E + j;
        #pragma unroll
        for (int r = 0; r < 4; ++r) {
          const ushort* g = gxp + (long)(kg*4 + r)*G3E;
          g0[r] = bf2f(g[0]); g1[r] = bf2f(g[512]); g2[r] = bf2f(g[1024]);
        }
      }
      #pragma unroll
      for (int r = 0; r < 4; ++r) {
        int b = kg*4 + r;
        long yi = bmajor ? ((long)b*TSN + t)*ldY + dir*512 + j
                         : ((long)t*NB + b)*1024 + dir*512 + j;
        Ybf[yi] = f2bf(hsave[r]);
      }
      if (tid < 8) {
        while ((int)agat_ld((const unsigned*)(dslots + tid*32)) < s + 1)
          __builtin_amdgcn_s_sleep(1);
      }
      __syncthreads();
    } else {
      #pragma unroll
      for (int r = 0; r < 4; ++r) {
        int b = kg*4 + r;
        long yi = bmajor ? ((long)b*TSN + t)*ldY + dir*512 + j
                         : ((long)t*NB + b)*1024 + dir*512 + j;
        Ybf[yi] = f2bf(hsave[r]);
        hfin[b*1024 + dir*512 + j] = hsave[r];
      }
    }
  }
}

// ---------------- row softmax f32 -> bf16 (pad to 448) ----------------
__global__ __launch_bounds__(256) void k_softmax_bf(
    const float* __restrict__ E, ushort* __restrict__ S)
{
  long row = blockIdx.x;
  const float* x = E + row*TSN;
  ushort* o = S + row*448;
  int tid = threadIdx.x;
  float v0 = (tid < TSN) ? x[tid] : -INFINITY;
  float v1 = (tid + 256 < TSN) ? x[tid + 256] : -INFINITY;
  __shared__ float red[256];
  red[tid] = fmaxf(v0, v1); __syncthreads();
  for (int oo = 128; oo; oo >>= 1) { if (tid < oo) red[tid] = fmaxf(red[tid], red[tid+oo]); __syncthreads(); }
  float m = red[0]; __syncthreads();
  float e0 = (tid < TSN) ? expf(v0 - m) : 0.f;
  float e1 = (tid + 256 < TSN) ? expf(v1 - m) : 0.f;
  red[tid] = e0 + e1; __syncthreads();
  for (int oo = 128; oo; oo >>= 1) { if (tid < oo) red[tid] += red[tid+oo]; __syncthreads(); }
  float inv = 1.f/red[0];
  if (tid < 192) o[tid + 256] = (tid + 256 < TSN) ? f2bf(e1*inv) : (ushort)0;
  o[tid] = f2bf(e0*inv);
}

// ---------------- fused selfcomb (raw preacts) + answer attention -> encbf ----------------
__global__ __launch_bounds__(256) void k_ansatt2(
    const ushort* __restrict__ memsb, const ushort* __restrict__ ftgt,
    const ushort* __restrict__ outpb,   // stride 2048 (catE lower half)
    const int* __restrict__ input_a, ushort* __restrict__ encb)
{
  int b = blockIdx.x >> 2;
  int d = (blockIdx.x & 3)*256 + threadIdx.x;
  __shared__ int ia[TSN];
  for (int i = threadIdx.x; i < TSN; i += 256) ia[i] = input_a[b*TSN + i];
  __syncthreads();
  float m = -INFINITY;
  #pragma unroll 4
  for (int t = 0; t < TSN; ++t) {
    float v = bf2f(memsb[((long)b*TSN + t)*1024 + d]);
    float e = ia[t] ? v*v : v;
    m = fmaxf(m, e);
  }
  float ssum = 0.f;
  #pragma unroll 4
  for (int t = 0; t < TSN; ++t) {
    float v = bf2f(memsb[((long)b*TSN + t)*1024 + d]);
    float e = ia[t] ? v*v : v;
    ssum += expf(e - m);
  }
  float inv = 1.f/ssum;
  #pragma unroll 4
  for (int t = 0; t < TSN; ++t) {
    long idx = ((long)b*TSN + t)*1024 + d;
    long idx2 = ((long)b*TSN + t)*2048 + d;
    float v = bf2f(memsb[idx]);
    float e = ia[t] ? v*v : v;
    float fraw = bf2f(ftgt[idx2]);
    float graw = bf2f(ftgt[idx2 + 1024]);
    float gg = 1.f/(1.f + expf(-graw));
    float selfo = gg*tanhf(fraw) + (1.f - gg)*bf2f(outpb[idx2]);
    encb[idx] = f2bf(selfo + expf(e - m)*inv*v);
  }
}

// ---------------- decoder GRU layer: 64 blocks x 128 (2 waves split K) ----------------
__global__ __launch_bounds__(128) void k_gru_dec(
    const ushort* __restrict__ A1, const ushort* __restrict__ W1,
    const ushort* __restrict__ A2, const ushort* __restrict__ W2,
    const float* __restrict__ gxadd, const float* __restrict__ bi,
    const float* __restrict__ bh,
    const float* __restrict__ hprev, float* __restrict__ hout,
    ushort* __restrict__ houtb, ushort* __restrict__ catb)
{
  const int wv = threadIdx.x >> 6;
  const int lane = threadIdx.x & 63;
  const int lr = lane & 15, kg = lane >> 4;
  const int j = blockIdx.x*16 + lr;
  const int kb = wv*512;
  __shared__ float psum[6][16][16];
  const ushort* w1p0 = W1 + ((long)(j)        << 10) + kb + kg*8;
  const ushort* w1p1 = W1 + ((long)(1024 + j) << 10) + kb + kg*8;
  const ushort* w1p2 = W1 + ((long)(2048 + j) << 10) + kb + kg*8;
  const ushort* w2p0 = W2 + ((long)(j)        << 10) + kb + kg*8;
  const ushort* w2p1 = W2 + ((long)(1024 + j) << 10) + kb + kg*8;
  const ushort* w2p2 = W2 + ((long)(2048 + j) << 10) + kb + kg*8;
  const ushort* a1p = A1 + lr*1024 + kb + kg*8;
  const ushort* a2p = A2 + lr*1024 + kb + kg*8;
  f32x4 x0 = {}, x1 = {}, x2 = {}, h0 = {}, h1 = {}, h2 = {};
  #pragma unroll 4
  for (int k0 = 0; k0 < 512; k0 += 32) {
    bf16x8 a1v = *(const bf16x8*)(a1p + k0);
    bf16x8 a2v = *(const bf16x8*)(a2p + k0);
    x0 = __builtin_amdgcn_mfma_f32_16x16x32_bf16(a1v, *(const bf16x8*)(w1p0 + k0), x0, 0, 0, 0);
    x1 = __builtin_amdgcn_mfma_f32_16x16x32_bf16(a1v, *(const bf16x8*)(w1p1 + k0), x1, 0, 0, 0);
    x2 = __builtin_amdgcn_mfma_f32_16x16x32_bf16(a1v, *(const bf16x8*)(w1p2 + k0), x2, 0, 0, 0);
    h0 = __builtin_amdgcn_mfma_f32_16x16x32_bf16(a2v, *(const bf16x8*)(w2p0 + k0), h0, 0, 0, 0);
    h1 = __builtin_amdgcn_mfma_f32_16x16x32_bf16(a2v, *(const bf16x8*)(w2p1 + k0), h1, 0, 0, 0);
    h2 = __builtin_amdgcn_mfma_f32_16x16x32_bf16(a2v, *(const bf16x8*)(w2p2 + k0), h2, 0, 0, 0);
  }
  if (wv == 1) {
    #pragma unroll
    for (int r = 0; r < 4; ++r) {
      int b = kg*4 + r;
      psum[0][b][lr] = x0[r]; psum[1][b][lr] = x1[r]; psum[2][b][lr] = x2[r];
      psum[3][b][lr] = h0[r]; psum[4][b][lr] = h1[r]; psum[5][b][lr] = h2[r];
    }
  }
  __syncthreads();
  if (wv == 0) {
    float bi0 = bi ? bi[j] : 0.f, bi1 = bi ? bi[1024 + j] : 0.f, bi2 = bi ? bi[2048 + j] : 0.f;
    float bh0 = bh[j], bh1 = bh[1024 + j], bh2 = bh[2048 + j];
    #pragma unroll
    for (int r = 0; r < 4; ++r) {
      int b = kg*4 + r;
      float gxa0 = gxadd ? gxadd[(long)b*G3D + j]        : 0.f;
      float gxa1 = gxadd ? gxadd[(long)b*G3D + 1024 + j] : 0.f;
      float gxa2 = gxadd ? gxadd[(long)b*G3D + 2048 + j] : 0.f;
      float gx0 = x0[r] + psum[0][b][lr] + gxa0 + bi0;
      float gx1 = x1[r] + psum[1][b][lr] + gxa1 + bi1;
      float gx2 = x2[r] + psum[2][b][lr] + gxa2 + bi2;
      float gh0 = h0[r] + psum[3][b][lr] + bh0;
      float gh1 = h1[r] + psum[4][b][lr] + bh1;
      float gh2 = h2[r] + psum[5][b][lr] + bh2;
      float rr = 1.f/(1.f + expf(-(gx0 + gh0)));
      float zz = 1.f/(1.f + expf(-(gx1 + gh1)));
      float nn = tanhf(gx2 + rr*gh2);
      float hp = hprev[b*1024 + j];
      float hn = (1.f - zz)*nn + zz*hp;
      hout[b*1024 + j] = hn;
      houtb[b*1024 + j] = f2bf(hn);
      if (catb) catb[(long)b*2048 + j] = f2bf(hn);
    }
  }
}

// ---------------- fused decoder attention v3: 64 blocks, per-b 4-slot barrier ----------------
__global__ __launch_bounds__(256) void k_dec_attn3(
    const ushort* __restrict__ h1b, const ushort* __restrict__ memdb,
    float* __restrict__ cov, float* __restrict__ coveS, float* __restrict__ covacc,
    float* __restrict__ scb,
    ushort* __restrict__ ctxn, ushort* __restrict__ catb,
    int* __restrict__ slots, int epoch)
{
  const int bid = blockIdx.x, tid = threadIdx.x;
  const int b = bid >> 2, q = bid & 3;
  const int wv = tid >> 6, lane = tid & 63;
  __shared__ float at[TSN];
  __shared__ float red[256];
  __shared__ float psD[4][64][4];
  float hr[16];
  {
    bf16x8 hv0 = *(const bf16x8*)&h1b[b*1024 + lane*16];
    bf16x8 hv1 = *(const bf16x8*)&h1b[b*1024 + lane*16 + 8];
    #pragma unroll
    for (int e = 0; e < 8; ++e) { hr[e] = bf2f((ushort)hv0[e]); hr[8+e] = bf2f((ushort)hv1[e]); }
  }
  #pragma unroll 2
  for (int i = 0; i < 25; ++i) {
    int t = q*100 + wv*25 + i;
    const ushort* row = memdb + ((long)b*TSN + t)*1024 + lane*16;
    bf16x8 r0 = *(const bf16x8*)row;
    bf16x8 r1 = *(const bf16x8*)(row + 8);
    float p = 0.f;
    #pragma unroll
    for (int e = 0; e < 8; ++e) p += hr[e]*bf2f((ushort)r0[e]) + hr[8+e]*bf2f((ushort)r1[e]);
    #pragma unroll
    for (int off = 32; off; off >>= 1) p += __shfl_xor(p, off);
    if (lane == 0) agat_st((unsigned*)&scb[b*TSN + t], __float_as_uint(p));
  }
  asm volatile("s_waitcnt vmcnt(0)" ::: "memory");
  __syncthreads();
  if (tid == 0) agat_st((unsigned*)(slots + bid*32), (unsigned)epoch);
  if (tid < 4) {
    while ((int)agat_ld((const unsigned*)(slots + (b*4 + tid)*32)) < epoch)
      __builtin_amdgcn_s_sleep(1);
  }
  __syncthreads();
  {
    bool t1v = tid < 144;
    float sc0 = __uint_as_float(agat_ld((const unsigned*)&scb[b*TSN + tid]));
    float sc1 = t1v ? __uint_as_float(agat_ld((const unsigned*)&scb[b*TSN + 256 + tid])) : 0.f;
    float co0 = cov[b*TSN + tid];
    float co1 = t1v ? cov[b*TSN + 256 + tid] : 0.f;
    float ce0 = sc0*(1.f - co0);
    float ce1 = t1v ? sc1*(1.f - co1) : -INFINITY;
    red[tid] = fmaxf(ce0, ce1); __syncthreads();
    for (int o = 128; o; o >>= 1) { if (tid < o) red[tid] = fmaxf(red[tid], red[tid+o]); __syncthreads(); }
    float m = red[0]; __syncthreads();
    float ex0 = expf(ce0 - m), ex1 = t1v ? expf(ce1 - m) : 0.f;
    red[tid] = ex0 + ex1; __syncthreads();
    for (int o = 128; o; o >>= 1) { if (tid < o) red[tid] += red[tid+o]; __syncthreads(); }
    float inv = 1.f/red[0]; __syncthreads();
    float a0 = ex0*inv, a1 = ex1*inv;
    at[tid] = a0;
    if (t1v) at[256 + tid] = a1;
    if (q == 0) {
      coveS[b*TSN + tid] = ce0;
      if (t1v) coveS[b*TSN + 256 + tid] = ce1;
      cov[b*TSN + tid] = co0 + a0;
      if (t1v) cov[b*TSN + 256 + tid] = co1 + a1;
      red[tid] = fminf(a0, co0) + (t1v ? fminf(a1, co1) : 0.f);
      __syncthreads();
      for (int o = 128; o; o >>= 1) { if (tid < o) red[tid] += red[tid+o]; __syncthreads(); }
      if (tid == 0) atomicAdd(covacc, red[0]);
    }
  }
  __syncthreads();
  {
    float acc4[4] = {};
    const int d0 = q*256 + lane*4;
    const unsigned* base = (const unsigned*)memdb + (((long)b*TSN*1024 + d0) >> 1);
    for (int t = wv*100; t < wv*100 + 100; ++t) {
      float a = at[t];
      const unsigned* p = base + (long)t*512;
      unsigned dv0 = p[0], dv1 = p[1];
      acc4[0] += a*bf2f((ushort)(dv0 & 0xffffu));
      acc4[1] += a*bf2f((ushort)(dv0 >> 16));
      acc4[2] += a*bf2f((ushort)(dv1 & 0xffffu));
      acc4[3] += a*bf2f((ushort)(dv1 >> 16));
    }
    #pragma unroll
    for (int e = 0; e < 4; ++e) psD[wv][lane][e] = acc4[e];
    __syncthreads();
    if (wv == 0) {
      float c[4];
      #pragma unroll
      for (int e = 0; e < 4; ++e)
        c[e] = psD[0][lane][e] + psD[1][lane][e] + psD[2][lane][e] + psD[3][lane][e];
      unsigned w0 = (unsigned)f2bf(c[0]) | ((unsigned)f2bf(c[1]) << 16);
      unsigned w1 = (unsigned)f2bf(c[2]) | ((unsigned)f2bf(c[3]) << 16);
      unsigned* cp = (unsigned*)ctxn + ((b*1024 + d0) >> 1);
      cp[0] = w0; cp[1] = w1;
      unsigned* kp = (unsigned*)catb + (((long)b*2048 + 1024 + d0) >> 1);
      kp[0] = w0; kp[1] = w1;
    }
  }
}

// ---------------- hid = tanh(cat @ pW1^T + pb1): 64 blocks x 128 ----------------
__global__ __launch_bounds__(128) void k_hid(
    const ushort* __restrict__ catb, const ushort* __restrict__ W,
    const float* __restrict__ pb1, ushort* __restrict__ hidb)
{
  const int wv = threadIdx.x >> 6;
  const int lane = threadIdx.x & 63;
  const int lr = lane & 15, kg = lane >> 4;
  const int n = blockIdx.x*16 + lr;
  const int kb = wv*1024;
  __shared__ float ps[16][16];
  f32x4 acc = {};
  const ushort* ap = catb + lr*2048 + kb + kg*8;
  const ushort* wp = W + ((long)n << 11) + kb + kg*8;
  #pragma unroll 8
  for (int k0 = 0; k0 < 1024; k0 += 32)
    acc = __builtin_amdgcn_mfma_f32_16x16x32_bf16(*(const bf16x8*)(ap + k0), *(const bf16x8*)(wp + k0), acc, 0, 0, 0);
  if (wv == 1) {
    #pragma unroll
    for (int r = 0; r < 4; ++r) ps[kg*4 + r][lr] = acc[r];
  }
  __syncthreads();
  if (wv == 0) {
    float bv = pb1[n];
    #pragma unroll
    for (int r = 0; r < 4; ++r) {
      int b = kg*4 + r;
      hidb[b*1024 + n] = f2bf(tanhf(acc[r] + ps[b][lr] + bv));
    }
  }
}

// ---------------- batched logits ----------------
__global__ __launch_bounds__(256) void k_logits_all(
    const ushort* __restrict__ hidAll,
    const ushort* __restrict__ pW2b,
    const float* __restrict__ pb2,
    float* __restrict__ outp)
{
  const int wave = threadIdx.x >> 6, lane = threadIdx.x & 63;
  const int lr = lane & 15, kg = lane >> 4;
  const int n0 = blockIdx.x*256 + wave*64;
  const int m0 = blockIdx.y*128;
  f32x4 acc[8][4] = {};
  for (int k0 = 0; k0 < 1024; k0 += 32) {
    bf16x8 bfr[4];
    #pragma unroll
    for (int nt = 0; nt < 4; ++nt)
      bfr[nt] = *(const bf16x8*)&pW2b[(long)(n0 + nt*16 + lr)*1024 + k0 + kg*8];
    #pragma unroll
    for (int mt = 0; mt < 8; ++mt) {
      bf16x8 af = *(const bf16x8*)&hidAll[(long)(m0 + mt*16 + lr)*1024 + k0 + kg*8];
      #pragma unroll
      for (int nt = 0; nt < 4; ++nt)
        acc[mt][nt] = __builtin_amdgcn_mfma_f32_16x16x32_bf16(af, bfr[nt], acc[mt][nt], 0, 0, 0);
    }
  }
  #pragma unroll
  for (int nt = 0; nt < 4; ++nt) {
    int v = n0 + nt*16 + lr;
    if (v >= NEXT) continue;
    float pb = (v < NV) ? pb2[v] : 0.f;
    #pragma unroll
    for (int mt = 0; mt < 8; ++mt) {
      #pragma unroll
      for (int r = 0; r < 4; ++r) {
        int m = m0 + mt*16 + kg*4 + r;
        int s = m >> 4, b = m & 15;
        float e = (v < NV) ? (acc[mt][nt][r] + pb) : 0.f;
        if (e == 0.f) e = NEG_INF;
        outp[((long)b*NTT + s)*NEXT + v] = e;
      }
    }
  }
}

// ---------------- copy-scatter compose ----------------
__device__ __forceinline__ float dec_f(unsigned e) {
  return (e & 0x80000000u) ? __uint_as_float(e ^ 0x80000000u) : __uint_as_float(~e);
}
__global__ __launch_bounds__(512) void k_compose_all(
    const int* __restrict__ ids, const float* __restrict__ coveAll,
    unsigned* __restrict__ ubuf, float* __restrict__ outp)
{
  int b = blockIdx.x, tid = threadIdx.x;
  int v = 0;
  if (tid < TSN) v = ids[b*TSN + tid];
  unsigned* up = ubuf + (long)b*NEXT;
  for (int s = 0; s < NTT; ++s) {
    if (tid < TSN) {
      float ce = coveAll[((long)s*NB + b)*TSN + tid];
      unsigned bb = __float_as_uint(ce);
      unsigned enc = (bb & 0x80000000u) ? ~bb : (bb | 0x80000000u);
      atomicMax(&up[v], enc);
    }
    __syncthreads();
    if (tid < TSN) {
      unsigned u = __hip_atomic_load(&up[v], __ATOMIC_RELAXED, __HIP_MEMORY_SCOPE_AGENT);
      float o = dec_f(u);
      long oi = ((long)b*NTT + s)*NEXT + v;
      float e = outp[oi];
      if (e == NEG_INF) e = 0.f;
      float lg = e + o;
      if (lg == 0.f) lg = NEG_INF;
      outp[oi] = lg;
    }
    __syncthreads();
    if (tid < TSN)
      __hip_atomic_store(&up[v], 0u, __ATOMIC_RELAXED, __HIP_MEMORY_SCOPE_AGENT);
    __syncthreads();
  }
}

// ---------------- final coverage-loss scalar ----------------
__global__ void k_covout(const float* __restrict__ covacc, float* __restrict__ outp)
{
  outp[(long)NB*NTT*NEXT] = covacc[0] * (1.0f/(NB*NTT));
}

// ==================== host ====================
extern "C" void kernel_launch(void* const* d_in, const int* in_sizes, int n_in,
                              void* d_out, int out_size, void* d_ws, size_t ws_size,
                              hipStream_t stream) {
  (void)in_sizes; (void)n_in; (void)out_size; (void)ws_size;
  const float* enc_emb = (const float*)d_in[0];
  const float* ans_emb = (const float*)d_in[1];
  const float* dec_emb = (const float*)d_in[2];
  const float* eWi0 = (const float*)d_in[3];
  const float* eWh0 = (const float*)d_in[4];
  const float* ebi0 = (const float*)d_in[5];
  const float* ebh0 = (const float*)d_in[6];
  const float* eWi1 = (const float*)d_in[7];
  const float* eWh1 = (const float*)d_in[8];
  const float* ebi1 = (const float*)d_in[9];
  const float* ebh1 = (const float*)d_in[10];
  const float* trans_W = (const float*)d_in[11];
  const float* trans_b = (const float*)d_in[12];
  const float* upd_W = (const float*)d_in[13];
  const float* gate_W = (const float*)d_in[14];
  const float* dWi0 = (const float*)d_in[15];
  const float* dWh0 = (const float*)d_in[16];
  const float* dbi0 = (const float*)d_in[17];
  const float* dbh0 = (const float*)d_in[18];
  const float* dWi1 = (const float*)d_in[19];
  const float* dWh1 = (const float*)d_in[20];
  const float* dbi1 = (const float*)d_in[21];
  const float* dbh1 = (const float*)d_in[22];
  const float* dtrans_W = (const float*)d_in[23];
  const float* dtrans_b = (const float*)d_in[24];
  const float* pW1 = (const float*)d_in[25];
  const float* pb1 = (const float*)d_in[26];
  const float* pW2 = (const float*)d_in[27];
  const float* pb2 = (const float*)d_in[28];
  const int* input_s = (const int*)d_in[29];
  const int* ext_ids = (const int*)d_in[30];
  const int* input_q = (const int*)d_in[31];
  const int* input_a = (const int*)d_in[32];
  float* out = (float*)d_out;

  float* ws = (float*)d_ws;
  size_t off = 0;
  auto alloc = [&](size_t n) { float* p = ws + off; off += (n + 15) & ~(size_t)15; return p; };
  auto alloch = [&](size_t nh) { return (ushort*)alloc((nh + 1) / 2); };

  // --- small persistent ---
  ushort* hpp  = alloch(2ull*2*NB*HENC);
  int*   bar   = (int*)alloc(4096);
  float* covacc= alloc(4);
  float* cov   = alloc(NB*TSN);
  float* scb   = alloc(NB*TSN);
  unsigned* ubuf = (unsigned*)alloc((size_t)NB*NEXT);
  float* hfin0 = alloc(NB*HD2);
  float* hfin1 = alloc(NB*HD2);
  float* dh0   = alloc(2ull*NB*HD2);
  float* dh1   = alloc(2ull*NB*HD2);
  ushort* h0b  = alloch(2ull*NB*HD2);
  ushort* h1b  = alloch(2ull*NB*HD2);
  ushort* ctxbf= alloch(2ull*NB*HD2);
  ushort* catbf= alloch((size_t)NB*2048);
  ushort* hidAll = alloch((size_t)NTT*NB*HD2);
  float* coveAll = alloc((size_t)NTT*NB*TSN);

  // --- bf16 weights ---
  ushort* eWi0c   = alloch(2ull*G3E*384);
  ushort* eWi1c   = alloch(2ull*G3E*1024);
  ushort* Whb0    = alloch(2ull*G3E*HENC);
  ushort* Whb1    = alloch(2ull*G3E*HENC);
  ushort* transWb = alloch(1024ull*1024);
  ushort* fgWb    = alloch(2048ull*2048);
  ushort* dtransWb= alloch(1024ull*1024);
  ushort* dWi0e   = alloch(3072ull*320);
  ushort* dWi0c   = alloch(3072ull*1024);
  ushort* dWh0b   = alloch(3072ull*1024);
  ushort* dWi1b   = alloch(3072ull*1024);
  ushort* dWh1b   = alloch(3072ull*1024);
  ushort* pW1b    = alloch(1024ull*2048);

  // --- alias region: [GX(bf16) | X0c | Y0bf | pad] -> later ftgt_bf, then pW2b ---
  size_t regionStart = off;
  float*  GXr  = alloc(2ull*6400*G3E);
  ushort* GXbf = (ushort*)GXr;
  ushort* X0c  = alloch(6400ull*384);
  ushort* Y0bf = alloch(6400ull*1024);
  alloc(6400ull*HD2);
  ushort* ftgt_bf = (ushort*)(ws + regionStart);
  ushort* pW2b    = (ushort*)(ws + regionStart);
  ushort* outpTb  = (ushort*)(ws + regionStart + 26000000);

  // --- big buffers ---
  ushort* memsbf = alloch(6400ull*HD2);
  ushort* catE   = alloch(6400ull*2048);     // [6400][2048] = [enc_out | ctx]
  float*  energ  = alloc((size_t)NB*TSN*TSN);
  ushort* scoresb= alloch((size_t)NB*TSN*448);
  ushort* memd_bf= alloch(6400ull*HD2);
  ushort* encbf  = alloch(6400ull*HD2);
  ushort* embqb  = alloch(512ull*320);
  float*  embGX  = alloc(512ull*G3D);

  // ---------------- one-time casts ----------------
  k_embed_bf<<<9600, 256, 0, stream>>>(enc_emb, ans_emb, input_s, input_a, X0c);
  k_castw<<<4608, 256, 0, stream>>>(eWi0, eWi0c, 3072, 3072ull*384, 332, 384, 332, 0);
  {
    CJobs jobs;
    jobs.nj = 11;
    jobs.j[0]  = { (const float4*)eWi1,    eWi1c,               393216 };
    jobs.j[1]  = { (const float4*)eWh0,    Whb0,                196608 };
    jobs.j[2]  = { (const float4*)eWh1,    Whb1,                196608 };
    jobs.j[3]  = { (const float4*)trans_W, transWb,             131072 };
    jobs.j[4]  = { (const float4*)upd_W,   fgWb,                262144 };
    jobs.j[5]  = { (const float4*)gate_W,  fgWb + 1024ull*2048, 262144 };
    jobs.j[6]  = { (const float4*)dtrans_W, dtransWb,           131072 };
    jobs.j[7]  = { (const float4*)dWh0,    dWh0b,               393216 };
    jobs.j[8]  = { (const float4*)dWi1,    dWi1b,               393216 };
    jobs.j[9]  = { (const float4*)dWh1,    dWh1b,               393216 };
    jobs.j[10] = { (const float4*)pW1,     pW1b,                262144 };
    k_cast8_multi<<<2048, 256, 0, stream>>>(jobs);
  }
  k_castw<<<3840, 256, 0, stream>>>(dWi0, dWi0e, 3072, 3072ull*320, 300, 320, 1324, 0);
  k_castw<<<12288, 256, 0, stream>>>(dWi0, dWi0c, 3072, 3072ull*1024, 1024, 1024, 1324, 300);

  hipMemsetAsync(bar, 0, 16384, stream);

  // ---------------- encoder layer 0 ----------------
  k_mfma128<<<dim3(50,12,2), 256, 0, stream>>>(X0c, eWi0c, ebi0, GXbf,
      384, 384, 384, G3E, 0, (long)G3E*384, 6400ull*G3E, G3E);
  hipMemsetAsync(hpp, 0, 2ull*2*NB*HENC*2, stream);
  k_scan_mfma<<<16, 256, 0, stream>>>(GXbf, GXbf + 6400ull*G3E, Whb0, ebh0,
      Y0bf, 0, 1024, hfin0, hpp, bar);
  // ---------------- encoder layer 1 (writes catE lower half directly) ----------------
  k_mfma128<<<dim3(50,12,2), 256, 0, stream>>>(Y0bf, eWi1c, ebi1, GXbf,
      1024, 1024, 1024, G3E, 0, (long)G3E*1024, 6400ull*G3E, G3E);
  hipMemsetAsync(hpp, 0, 2ull*2*NB*HENC*2, stream);
  k_scan_mfma<<<16, 256, 0, stream>>>(GXbf, GXbf + 6400ull*G3E, Whb1, ebh1,
      catE, 1, 2048, hfin1, hpp, bar + 512);

  // ---------------- self/answer attention ----------------
  k_mfma128<<<dim3(50,8,1), 256, 0, stream>>>(catE, transWb, trans_b, memsbf,
      1024, 2048, 1024, 1024, 0, 0, 0, 0);
  k_mfma_nt<<<dim3(7,7,16), 256, 0, stream>>>(catE, memsbf, nullptr, energ, nullptr,
      TSN, TSN, 1024, 2048, 1024, TSN, (long)TSN*2048, (long)TSN*1024, (long)TSN*TSN, 0, 0, 0);
  k_softmax_bf<<<NB*TSN, 256, 0, stream>>>(energ, scoresb);
  k_transpose_hh<<<dim3(14,32,16), 256, 0, stream>>>(catE, outpTb, 2048);
  k_mfma_nt<<<dim3(7,16,16), 256, 0, stream>>>(scoresb, outpTb, nullptr, nullptr, catE + 1024,
      TSN, HD2, 448, 448, 448, 2048, (long)TSN*448, (long)HD2*448, (long)TSN*2048, 0, 0, 0);
  k_mfma128<<<dim3(50,16,1), 256, 0, stream>>>(catE, fgWb, nullptr, ftgt_bf,
      2048, 2048, 2048, 2048, 0, 0, 0, 0);
  k_ansatt2<<<64, 256, 0, stream>>>(memsbf, ftgt_bf, catE, input_a, encbf);
  // region dead after ansatt2: cast pW2 over it (vectorized) + zero pad rows
  k_cast8<<<25000, 256, 0, stream>>>((const float4*)pW2, pW2b, 6400000);
  hipMemsetAsync(pW2b + 50000l*1024, 0, 176l*1024*2, stream);
  k_mfma128<<<dim3(50,8,1), 256, 0, stream>>>(encbf, dtransWb, dtrans_b, memd_bf,
      1024, 1024, 1024, 1024, 0, 0, 0, 0);

  // ---------------- decoder precompute ----------------
  k_embq_bf<<<640, 256, 0, stream>>>(dec_emb, input_q, embqb);
  k_mfma_nt<<<dim3(8,48,1), 256, 0, stream>>>(embqb, dWi0e, dbi0, embGX, nullptr,
      NTT*NB, G3D, 320, 320, 320, G3D, 0, 0, 0, 0, 0, 0);

  hipMemsetAsync(cov, 0, (size_t)NB*TSN*4, stream);
  hipMemsetAsync(covacc, 0, 4, stream);
  hipMemsetAsync(ubuf, 0, (size_t)NB*NEXT*4, stream);
  hipMemsetAsync(ctxbf, 0, (size_t)NB*HD2*2, stream);
  hipMemcpyAsync(dh0, hfin0, (size_t)NB*HD2*4, hipMemcpyDeviceToDevice, stream);
  hipMemcpyAsync(dh1, hfin1, (size_t)NB*HD2*4, hipMemcpyDeviceToDevice, stream);
  k_cast<<<64, 256, 0, stream>>>(hfin0, h0b, 16384);
  k_cast<<<64, 256, 0, stream>>>(hfin1, h1b, 16384);

  // ---------------- decoder steps ----------------
  for (int s = 0; s < NTT; ++s) {
    int cur = s & 1, nxt = cur ^ 1;
    float* h0c = dh0 + (size_t)cur*NB*HD2;  float* h0n = dh0 + (size_t)nxt*NB*HD2;
    float* h1c = dh1 + (size_t)cur*NB*HD2;  float* h1n = dh1 + (size_t)nxt*NB*HD2;
    ushort* h0bc = h0b + (size_t)cur*NB*HD2; ushort* h0bn = h0b + (size_t)nxt*NB*HD2;
    ushort* h1bc = h1b + (size_t)cur*NB*HD2; ushort* h1bn = h1b + (size_t)nxt*NB*HD2;
    ushort* ctxc = ctxbf + (size_t)cur*NB*HD2; ushort* ctxn = ctxbf + (size_t)nxt*NB*HD2;

    k_gru_dec<<<64, 128, 0, stream>>>(ctxc, dWi0c, h0bc, dWh0b,
        embGX + (size_t)s*NB*G3D, nullptr, dbh0, h0c, h0n, h0bn, nullptr);
    k_gru_dec<<<64, 128, 0, stream>>>(h0bn, dWi1b, h1bc, dWh1b,
        nullptr, dbi1, dbh1, h1c, h1n, h1bn, catbf);
    k_dec_attn3<<<64, 256, 0, stream>>>(h1bn, memd_bf,
        cov, coveAll + (size_t)s*NB*TSN, covacc, scb, ctxn, catbf,
        bar + 1024, s + 1);
    k_hid<<<64, 128, 0, stream>>>(catbf, pW1b, pb1, hidAll + (size_t)s*NB*HD2);
  }
  // ---------------- batched logits + compose ----------------
  k_logits_all<<<dim3(196, 4), 256, 0, stream>>>(hidAll, pW2b, pb2, out);
  k_compose_all<<<NB, 512, 0, stream>>>(ext_ids, coveAll, ubuf, out);
  k_covout<<<1, 1, 0, stream>>>(covacc, out);
}

// Round 18
// 5659.915 us; speedup vs baseline: 1.0616x; 1.0616x over previous
//
#include <hip/hip_runtime.h>
#include <stdint.h>

#define TSN 400
#define NB 16
#define HENC 512
#define HD2 1024
#define G3E 1536
#define G3D 3072
#define EMBD 300
#define AEMB 32
#define NV 50000
#define NEXT 50100
#define NVP 50176
#define NTT 32
#define NEG_INF (-1.0e12f)

typedef __attribute__((ext_vector_type(8))) short bf16x8;
typedef __attribute__((ext_vector_type(4))) float f32x4;

struct CJob { const float4* s; ushort* d; long n8; };
struct CJobs { CJob j[12]; int nj; };

__device__ __forceinline__ ushort f2bf(float f) {
  unsigned u = __float_as_uint(f);
  unsigned r = (u + 0x7fffu + ((u >> 16) & 1u)) >> 16;
  return (ushort)r;
}
__device__ __forceinline__ float bf2f(ushort h) {
  return __uint_as_float((unsigned)h << 16);
}
__device__ __forceinline__ unsigned agat_ld(const unsigned* p) {
  return __hip_atomic_load(p, __ATOMIC_RELAXED, __HIP_MEMORY_SCOPE_AGENT);
}
__device__ __forceinline__ void agat_st(unsigned* p, unsigned v) {
  __hip_atomic_store(p, v, __ATOMIC_RELAXED, __HIP_MEMORY_SCOPE_AGENT);
}
__device__ __forceinline__ unsigned long long agat_ld64(const unsigned long long* p) {
  return __hip_atomic_load(p, __ATOMIC_RELAXED, __HIP_MEMORY_SCOPE_AGENT);
}

// ---------------- embeddings -> bf16, padded K=384 ----------------
__global__ __launch_bounds__(256) void k_embed_bf(
    const float* __restrict__ enc_emb, const float* __restrict__ ans_emb,
    const int* __restrict__ input_s, const int* __restrict__ input_a,
    ushort* __restrict__ X0)
{
  long i = (long)blockIdx.x*256 + threadIdx.x;
  if (i >= (long)TSN*NB*384) return;
  int c = (int)(i % 384);
  long r = i / 384;
  int b = (int)(r % NB);
  int t = (int)(r / NB);
  float v = 0.f;
  if (c < EMBD) v = enc_emb[(long)input_s[b*TSN + t]*EMBD + c];
  else if (c < 332) v = ans_emb[(long)input_a[b*TSN + t]*AEMB + (c - EMBD)];
  X0[i] = f2bf(v);
}

// ---------------- decoder emb -> bf16, padded K=320 ----------------
__global__ __launch_bounds__(256) void k_embq_bf(
    const float* __restrict__ dec_emb, const int* __restrict__ input_q,
    ushort* __restrict__ EQ)
{
  long i = (long)blockIdx.x*256 + threadIdx.x;
  if (i >= (long)NTT*NB*320) return;
  int c = (int)(i % 320);
  long r = i / 320;
  int b = (int)(r % NB);
  int s = (int)(r / NB);
  EQ[i] = (c < EMBD) ? f2bf(dec_emb[(long)input_q[b*33 + s]*EMBD + c]) : (ushort)0;
}

// ---------------- weight cast with pad (strided / padded cases) ----------------
__global__ __launch_bounds__(256) void k_castw(
    const float* __restrict__ src, ushort* __restrict__ dst,
    int Nsrc, long total, int Ksrc, int Kdst, int ldsrc, int coloff)
{
  long i = (long)blockIdx.x*256 + threadIdx.x;
  if (i >= total) return;
  int k = (int)(i % Kdst);
  long n = i / Kdst;
  float v = (n < Nsrc && k < Ksrc) ? src[n*ldsrc + coloff + k] : 0.f;
  dst[i] = f2bf(v);
}

// ---------------- vectorized contiguous cast ----------------
__global__ __launch_bounds__(256) void k_cast8(
    const float4* __restrict__ s, ushort* __restrict__ d, long n8)
{
  long i = (long)blockIdx.x*256 + threadIdx.x;
  if (i >= n8) return;
  float4 v0 = s[2*i], v1 = s[2*i + 1];
  union { ushort u[8]; bf16x8 h; } c;
  c.u[0] = f2bf(v0.x); c.u[1] = f2bf(v0.y); c.u[2] = f2bf(v0.z); c.u[3] = f2bf(v0.w);
  c.u[4] = f2bf(v1.x); c.u[5] = f2bf(v1.y); c.u[6] = f2bf(v1.z); c.u[7] = f2bf(v1.w);
  *(bf16x8*)&d[i*8] = c.h;
}

// ---------------- multi-job contiguous cast (one launch) ----------------
__global__ __launch_bounds__(256) void k_cast8_multi(CJobs jobs)
{
  const long stride = (long)gridDim.x*256;
  for (int ji = 0; ji < jobs.nj; ++ji) {
    const float4* s = jobs.j[ji].s;
    ushort* d = jobs.j[ji].d;
    const long n8 = jobs.j[ji].n8;
    for (long i = (long)blockIdx.x*256 + threadIdx.x; i < n8; i += stride) {
      float4 v0 = s[2*i], v1 = s[2*i + 1];
      union { ushort u[8]; bf16x8 h; } c;
      c.u[0] = f2bf(v0.x); c.u[1] = f2bf(v0.y); c.u[2] = f2bf(v0.z); c.u[3] = f2bf(v0.w);
      c.u[4] = f2bf(v1.x); c.u[5] = f2bf(v1.y); c.u[6] = f2bf(v1.z); c.u[7] = f2bf(v1.w);
      *(bf16x8*)&d[i*8] = c.h;
    }
  }
}

// ---------------- plain cast fp32 -> bf16 ----------------
__global__ __launch_bounds__(256) void k_cast(
    const float* __restrict__ s, ushort* __restrict__ d, long n)
{
  long i = (long)blockIdx.x*256 + threadIdx.x;
  if (i >= n) return;
  d[i] = f2bf(s[i]);
}

// ---------------- bf16 batched transpose with K-pad: out[b][c][r(448)] ----------------
__global__ __launch_bounds__(256) void k_transpose_hh(
    const ushort* __restrict__ in, ushort* __restrict__ out, int ldin)
{
  __shared__ ushort tb[32][33];
  int b = blockIdx.z;
  int r0 = blockIdx.x*32, c0 = blockIdx.y*32;
  int tx = threadIdx.x & 31, ty = threadIdx.x >> 5;
  #pragma unroll
  for (int i = 0; i < 32; i += 8) {
    int r = r0 + ty + i, c = c0 + tx;
    tb[ty+i][tx] = (r < TSN) ? in[((long)b*TSN + r)*ldin + c] : (ushort)0;
  }
  __syncthreads();
  #pragma unroll
  for (int i = 0; i < 32; i += 8) {
    int c = c0 + ty + i, r = r0 + tx;
    out[((long)b*1024 + c)*448 + r] = tb[tx][ty+i];
  }
}

// ---------------- MFMA GEMM 64x64 (fp32 C optional; bf16 C2 optional) ----------------
__global__ __launch_bounds__(256) void k_mfma_nt(
    const ushort* __restrict__ Ab, const ushort* __restrict__ Wb,
    const float* __restrict__ bias, float* __restrict__ Cb, ushort* __restrict__ C2b,
    int M, int N, int K, int lda, int ldw, int ldc,
    long sA, long sW, long sC, long sBias, int accum, int act)
{
  __shared__ ushort As[64][72];
  __shared__ ushort Ws[64][72];
  const ushort* A = Ab + (long)blockIdx.z * sA;
  const ushort* W = Wb + (long)blockIdx.z * sW;
  float* C = Cb ? Cb + (long)blockIdx.z * sC : nullptr;
  const float* bi = bias ? bias + (long)blockIdx.z * sBias : nullptr;
  const int m0 = blockIdx.x*64, n0 = blockIdx.y*64;
  const int tid = threadIdx.x;
  const int wave = tid >> 6, lane = tid & 63;
  const int wm = wave >> 1, wn = wave & 1;
  const int lr = lane & 15, kg = lane >> 4;
  f32x4 acc[2][2] = {};
  for (int k0 = 0; k0 < K; k0 += 64) {
    __syncthreads();
    #pragma unroll
    for (int it = 0; it < 2; ++it) {
      int sidx = tid + it*256;
      int r = sidx >> 3, c = (sidx & 7)*8;
      bf16x8 av = {};
      bf16x8 wv = {};
      if (m0 + r < M) av = *(const bf16x8*)&A[(long)(m0+r)*lda + k0 + c];
      if (n0 + r < N) wv = *(const bf16x8*)&W[(long)(n0+r)*ldw + k0 + c];
      *(bf16x8*)&As[r][c] = av;
      *(bf16x8*)&Ws[r][c] = wv;
    }
    __syncthreads();
    #pragma unroll
    for (int kk = 0; kk < 2; ++kk) {
      bf16x8 af[2], bf[2];
      #pragma unroll
      for (int mt = 0; mt < 2; ++mt)
        af[mt] = *(const bf16x8*)&As[wm*32 + mt*16 + lr][kk*32 + kg*8];
      #pragma unroll
      for (int nt = 0; nt < 2; ++nt)
        bf[nt] = *(const bf16x8*)&Ws[wn*32 + nt*16 + lr][kk*32 + kg*8];
      #pragma unroll
      for (int mt = 0; mt < 2; ++mt)
        #pragma unroll
        for (int nt = 0; nt < 2; ++nt)
          acc[mt][nt] = __builtin_amdgcn_mfma_f32_16x16x32_bf16(af[mt], bf[nt], acc[mt][nt], 0, 0, 0);
    }
  }
  #pragma unroll
  for (int mt = 0; mt < 2; ++mt) {
    #pragma unroll
    for (int r = 0; r < 4; ++r) {
      int m = m0 + wm*32 + mt*16 + kg*4 + r;
      if (m >= M) continue;
      #pragma unroll
      for (int nt = 0; nt < 2; ++nt) {
        int n = n0 + wn*32 + nt*16 + lr;
        if (n >= N) continue;
        float v = acc[mt][nt][r];
        if (accum && C) v += C[(long)m*ldc + n];
        if (bi)    v += bi[n];
        if (act == 1) v = tanhf(v);
        else if (act == 2) v = 1.f/(1.f + expf(-v));
        if (C) C[(long)m*ldc + n] = v;
        if (C2b) C2b[(long)blockIdx.z*sC + (long)m*ldc + n] = f2bf(v);
      }
    }
  }
}

// ---------------- MFMA GEMM 128x128 (guard-free, bias optional, bf16 out) ----------------
__global__ __launch_bounds__(256) void k_mfma128(
    const ushort* __restrict__ Ab, const ushort* __restrict__ Wb,
    const float* __restrict__ bias, ushort* __restrict__ C2b,
    int K, int lda, int ldw, int ldc,
    long sA, long sW, long sC, long sBias)
{
  __shared__ ushort As[128][72];
  __shared__ ushort Ws[128][72];
  const ushort* A = Ab + (long)blockIdx.z * sA;
  const ushort* W = Wb + (long)blockIdx.z * sW;
  ushort* C2 = C2b + (long)blockIdx.z * sC;
  const float* bi = bias ? bias + (long)blockIdx.z * sBias : nullptr;
  const int m0 = blockIdx.x*128, n0 = blockIdx.y*128;
  const int tid = threadIdx.x;
  const int wave = tid >> 6, lane = tid & 63;
  const int wm = wave >> 1, wn = wave & 1;
  const int lr = lane & 15, kg = lane >> 4;
  f32x4 acc[4][4] = {};
  for (int k0 = 0; k0 < K; k0 += 64) {
    __syncthreads();
    #pragma unroll
    for (int it = 0; it < 4; ++it) {
      int idx = it*256 + tid;
      int r = idx >> 3, c = (idx & 7)*8;
      *(bf16x8*)&As[r][c] = *(const bf16x8*)&A[(long)(m0+r)*lda + k0 + c];
      *(bf16x8*)&Ws[r][c] = *(const bf16x8*)&W[(long)(n0+r)*ldw + k0 + c];
    }
    __syncthreads();
    #pragma unroll
    for (int kk = 0; kk < 2; ++kk) {
      bf16x8 af[4], bfv[4];
      #pragma unroll
      for (int mt = 0; mt < 4; ++mt)
        af[mt] = *(const bf16x8*)&As[wm*64 + mt*16 + lr][kk*32 + kg*8];
      #pragma unroll
      for (int nt = 0; nt < 4; ++nt)
        bfv[nt] = *(const bf16x8*)&Ws[wn*64 + nt*16 + lr][kk*32 + kg*8];
      #pragma unroll
      for (int mt = 0; mt < 4; ++mt)
        #pragma unroll
        for (int nt = 0; nt < 4; ++nt)
          acc[mt][nt] = __builtin_amdgcn_mfma_f32_16x16x32_bf16(af[mt], bfv[nt], acc[mt][nt], 0, 0, 0);
    }
  }
  #pragma unroll
  for (int mt = 0; mt < 4; ++mt) {
    #pragma unroll
    for (int r = 0; r < 4; ++r) {
      int m = m0 + wm*64 + mt*16 + kg*4 + r;
      #pragma unroll
      for (int nt = 0; nt < 4; ++nt) {
        int n = n0 + wn*64 + nt*16 + lr;
        float v = acc[mt][nt][r];
        if (bi) v += bi[n];
        C2[(long)m*ldc + n] = f2bf(v);
      }
    }
  }
}

// ---------------- persistent MFMA bidirectional GRU scan v6 + XCD-local remap ----------------
// Launched with grid 121; only bid%8==0 blocks work (sid=bid/8, 16 workers all on
// one XCD under round-robin dispatch) so the h-exchange sync stays in one L2.
__global__ __launch_bounds__(256, 1) void k_scan_mfma(
    const ushort* __restrict__ GXf, const ushort* __restrict__ GXb,
    const ushort* __restrict__ Whb,
    const float* __restrict__ bh,
    ushort* __restrict__ Ybf, int bmajor, int ldY,
    float* __restrict__ hfin,
    ushort* __restrict__ hpp,
    int* __restrict__ slots)
{
  const int bidx = blockIdx.x;
  if (bidx & 7) return;
  const int sid = bidx >> 3;          // 0..15
  const int tid = threadIdx.x;
  const int wg = sid*4 + (tid >> 6);
  const int lane = tid & 63;
  const int lr = lane & 15, kg = lane >> 4;
  const int dir = wg >> 5, jt = wg & 31;
  const int j = jt*16 + lr;
  __shared__ ushort hsm[16][520];
  const ushort* Wp0 = Whb + ((long)(dir*G3E + j)        << 9) + kg*8;
  const ushort* Wp1 = Whb + ((long)(dir*G3E + 512 + j)  << 9) + kg*8;
  const ushort* Wp2 = Whb + ((long)(dir*G3E + 1024 + j) << 9) + kg*8;
  bf16x8 W0[16], W1[16], W2[16];
  #pragma unroll
  for (int i = 0; i < 16; ++i) {
    W0[i] = *(const bf16x8*)(Wp0 + i*32);
    W1[i] = *(const bf16x8*)(Wp1 + i*32);
    W2[i] = *(const bf16x8*)(Wp2 + i*32);
  }
  const float bh0 = bh[dir*G3E + j];
  const float bh1 = bh[dir*G3E + 512 + j];
  const float bh2 = bh[dir*G3E + 1024 + j];
  const ushort* GX = dir ? GXb : GXf;
  unsigned* hppu = (unsigned*)hpp;
  int* myslot = slots + dir*256 + (sid & 7)*32;
  int* dslots = slots + dir*256;
  float hreg[4] = {0.f, 0.f, 0.f, 0.f};
  float g0[4], g1[4], g2[4];
  {
    const int t0 = dir ? (TSN - 1) : 0;
    const ushort* gxp = GX + (long)t0*NB*G3E + j;
    #pragma unroll
    for (int r = 0; r < 4; ++r) {
      const ushort* g = gxp + (long)(kg*4 + r)*G3E;
      g0[r] = bf2f(g[0]); g1[r] = bf2f(g[512]); g2[r] = bf2f(g[1024]);
    }
  }
  for (int s = 0; s < TSN; ++s) {
    const int cur = s & 1;
    {
      const unsigned long long* hin =
          (const unsigned long long*)hppu + (cur*2 + dir)*2048;
      unsigned long long vqw[8];
      #pragma unroll
      for (int i = 0; i < 8; ++i) vqw[i] = agat_ld64(hin + i*256 + tid);
      #pragma unroll
      for (int i = 0; i < 8; ++i) {
        int d0 = 2*(i*256 + tid);
        *(unsigned long long*)&hsm[d0 >> 8][(d0 & 255)*2] = vqw[i];
      }
    }
    __syncthreads();
    f32x4 a0 = {}, a1 = {}, a2 = {};
    #pragma unroll
    for (int i = 0; i < 16; ++i) {
      bf16x8 hf = *(const bf16x8*)&hsm[lr][kg*8 + i*32];
      a0 = __builtin_amdgcn_mfma_f32_16x16x32_bf16(hf, W0[i], a0, 0, 0, 0);
      a1 = __builtin_amdgcn_mfma_f32_16x16x32_bf16(hf, W1[i], a1, 0, 0, 0);
      a2 = __builtin_amdgcn_mfma_f32_16x16x32_bf16(hf, W2[i], a2, 0, 0, 0);
    }
    const int t = dir ? (TSN - 1 - s) : s;
    const int obase = ((cur^1)*2 + dir)*16*512;
    float hsave[4];
    #pragma unroll
    for (int r = 0; r < 4; ++r) {
      int b = kg*4 + r;
      float rr = 1.f/(1.f + expf(-(g0[r] + a0[r] + bh0)));
      float zz = 1.f/(1.f + expf(-(g1[r] + a1[r] + bh1)));
      float nn = tanhf(g2[r] + rr*(a2[r] + bh2));
      float hn = (1.f - zz)*nn + zz*hreg[r];
      hreg[r] = hn;
      hsave[r] = hn;
      unsigned hv = f2bf(hn);
      unsigned pv = (unsigned)__shfl_xor((int)hv, 1);
      if ((lr & 1) == 0)
        agat_st(hppu + ((obase + b*512 + j) >> 1), hv | (pv << 16));
    }
    if (s + 1 < TSN) {
      asm volatile("s_waitcnt vmcnt(0)" ::: "memory");
      __syncthreads();
      if (tid == 0)
        agat_st((unsigned*)myslot, (unsigned)(s + 1));
      {
        const int tn = dir ? (TSN - 2 - s) : (s + 1);
        const ushort* gxp = GX + (long)tn*NB*G3E + j;
        #pragma unroll
        for (int r = 0; r < 4; ++r) {
          const ushort* g = gxp + (long)(kg*4 + r)*G3E;
          g0[r] = bf2f(g[0]); g1[r] = bf2f(g[512]); g2[r] = bf2f(g[1024]);
        }
      }
      #pragma unroll
      for (int r = 0; r < 4; ++r) {
        int b = kg*4 + r;
        long yi = bmajor ? ((long)b*TSN + t)*ldY + dir*512 + j
                         : ((long)t*NB + b)*1024 + dir*512 + j;
        Ybf[yi] = f2bf(hsave[r]);
      }
      if (tid < 8) {
        while ((int)agat_ld((const unsigned*)(dslots + tid*32)) < s + 1)
          __builtin_amdgcn_s_sleep(1);
      }
      __syncthreads();
    } else {
      #pragma unroll
      for (int r = 0; r < 4; ++r) {
        int b = kg*4 + r;
        long yi = bmajor ? ((long)b*TSN + t)*ldY + dir*512 + j
                         : ((long)t*NB + b)*1024 + dir*512 + j;
        Ybf[yi] = f2bf(hsave[r]);
        hfin[b*1024 + dir*512 + j] = hsave[r];
      }
    }
  }
}

// ---------------- row softmax f32 -> bf16 (pad to 448) ----------------
__global__ __launch_bounds__(256) void k_softmax_bf(
    const float* __restrict__ E, ushort* __restrict__ S)
{
  long row = blockIdx.x;
  const float* x = E + row*TSN;
  ushort* o = S + row*448;
  int tid = threadIdx.x;
  float v0 = (tid < TSN) ? x[tid] : -INFINITY;
  float v1 = (tid + 256 < TSN) ? x[tid + 256] : -INFINITY;
  __shared__ float red[256];
  red[tid] = fmaxf(v0, v1); __syncthreads();
  for (int oo = 128; oo; oo >>= 1) { if (tid < oo) red[tid] = fmaxf(red[tid], red[tid+oo]); __syncthreads(); }
  float m = red[0]; __syncthreads();
  float e0 = (tid < TSN) ? expf(v0 - m) : 0.f;
  float e1 = (tid + 256 < TSN) ? expf(v1 - m) : 0.f;
  red[tid] = e0 + e1; __syncthreads();
  for (int oo = 128; oo; oo >>= 1) { if (tid < oo) red[tid] += red[tid+oo]; __syncthreads(); }
  float inv = 1.f/red[0];
  if (tid < 192) o[tid + 256] = (tid + 256 < TSN) ? f2bf(e1*inv) : (ushort)0;
  o[tid] = f2bf(e0*inv);
}

// ---------------- fused selfcomb (raw preacts) + answer attention -> encbf ----------------
__global__ __launch_bounds__(256) void k_ansatt2(
    const ushort* __restrict__ memsb, const ushort* __restrict__ ftgt,
    const ushort* __restrict__ outpb,   // stride 2048 (catE lower half)
    const int* __restrict__ input_a, ushort* __restrict__ encb)
{
  int b = blockIdx.x >> 2;
  int d = (blockIdx.x & 3)*256 + threadIdx.x;
  __shared__ int ia[TSN];
  for (int i = threadIdx.x; i < TSN; i += 256) ia[i] = input_a[b*TSN + i];
  __syncthreads();
  float m = -INFINITY;
  #pragma unroll 4
  for (int t = 0; t < TSN; ++t) {
    float v = bf2f(memsb[((long)b*TSN + t)*1024 + d]);
    float e = ia[t] ? v*v : v;
    m = fmaxf(m, e);
  }
  float ssum = 0.f;
  #pragma unroll 4
  for (int t = 0; t < TSN; ++t) {
    float v = bf2f(memsb[((long)b*TSN + t)*1024 + d]);
    float e = ia[t] ? v*v : v;
    ssum += expf(e - m);
  }
  float inv = 1.f/ssum;
  #pragma unroll 4
  for (int t = 0; t < TSN; ++t) {
    long idx = ((long)b*TSN + t)*1024 + d;
    long idx2 = ((long)b*TSN + t)*2048 + d;
    float v = bf2f(memsb[idx]);
    float e = ia[t] ? v*v : v;
    float fraw = bf2f(ftgt[idx2]);
    float graw = bf2f(ftgt[idx2 + 1024]);
    float gg = 1.f/(1.f + expf(-graw));
    float selfo = gg*tanhf(fraw) + (1.f - gg)*bf2f(outpb[idx2]);
    encb[idx] = f2bf(selfo + expf(e - m)*inv*v);
  }
}

// ---------------- decoder GRU layer: 64 blocks x 128 (2 waves split K) ----------------
__global__ __launch_bounds__(128) void k_gru_dec(
    const ushort* __restrict__ A1, const ushort* __restrict__ W1,
    const ushort* __restrict__ A2, const ushort* __restrict__ W2,
    const float* __restrict__ gxadd, const float* __restrict__ bi,
    const float* __restrict__ bh,
    const float* __restrict__ hprev, float* __restrict__ hout,
    ushort* __restrict__ houtb, ushort* __restrict__ catb)
{
  const int wv = threadIdx.x >> 6;
  const int lane = threadIdx.x & 63;
  const int lr = lane & 15, kg = lane >> 4;
  const int j = blockIdx.x*16 + lr;
  const int kb = wv*512;
  __shared__ float psum[6][16][16];
  const ushort* w1p0 = W1 + ((long)(j)        << 10) + kb + kg*8;
  const ushort* w1p1 = W1 + ((long)(1024 + j) << 10) + kb + kg*8;
  const ushort* w1p2 = W1 + ((long)(2048 + j) << 10) + kb + kg*8;
  const ushort* w2p0 = W2 + ((long)(j)        << 10) + kb + kg*8;
  const ushort* w2p1 = W2 + ((long)(1024 + j) << 10) + kb + kg*8;
  const ushort* w2p2 = W2 + ((long)(2048 + j) << 10) + kb + kg*8;
  const ushort* a1p = A1 + lr*1024 + kb + kg*8;
  const ushort* a2p = A2 + lr*1024 + kb + kg*8;
  f32x4 x0 = {}, x1 = {}, x2 = {}, h0 = {}, h1 = {}, h2 = {};
  #pragma unroll 4
  for (int k0 = 0; k0 < 512; k0 += 32) {
    bf16x8 a1v = *(const bf16x8*)(a1p + k0);
    bf16x8 a2v = *(const bf16x8*)(a2p + k0);
    x0 = __builtin_amdgcn_mfma_f32_16x16x32_bf16(a1v, *(const bf16x8*)(w1p0 + k0), x0, 0, 0, 0);
    x1 = __builtin_amdgcn_mfma_f32_16x16x32_bf16(a1v, *(const bf16x8*)(w1p1 + k0), x1, 0, 0, 0);
    x2 = __builtin_amdgcn_mfma_f32_16x16x32_bf16(a1v, *(const bf16x8*)(w1p2 + k0), x2, 0, 0, 0);
    h0 = __builtin_amdgcn_mfma_f32_16x16x32_bf16(a2v, *(const bf16x8*)(w2p0 + k0), h0, 0, 0, 0);
    h1 = __builtin_amdgcn_mfma_f32_16x16x32_bf16(a2v, *(const bf16x8*)(w2p1 + k0), h1, 0, 0, 0);
    h2 = __builtin_amdgcn_mfma_f32_16x16x32_bf16(a2v, *(const bf16x8*)(w2p2 + k0), h2, 0, 0, 0);
  }
  if (wv == 1) {
    #pragma unroll
    for (int r = 0; r < 4; ++r) {
      int b = kg*4 + r;
      psum[0][b][lr] = x0[r]; psum[1][b][lr] = x1[r]; psum[2][b][lr] = x2[r];
      psum[3][b][lr] = h0[r]; psum[4][b][lr] = h1[r]; psum[5][b][lr] = h2[r];
    }
  }
  __syncthreads();
  if (wv == 0) {
    float bi0 = bi ? bi[j] : 0.f, bi1 = bi ? bi[1024 + j] : 0.f, bi2 = bi ? bi[2048 + j] : 0.f;
    float bh0 = bh[j], bh1 = bh[1024 + j], bh2 = bh[2048 + j];
    #pragma unroll
    for (int r = 0; r < 4; ++r) {
      int b = kg*4 + r;
      float gxa0 = gxadd ? gxadd[(long)b*G3D + j]        : 0.f;
      float gxa1 = gxadd ? gxadd[(long)b*G3D + 1024 + j] : 0.f;
      float gxa2 = gxadd ? gxadd[(long)b*G3D + 2048 + j] : 0.f;
      float gx0 = x0[r] + psum[0][b][lr] + gxa0 + bi0;
      float gx1 = x1[r] + psum[1][b][lr] + gxa1 + bi1;
      float gx2 = x2[r] + psum[2][b][lr] + gxa2 + bi2;
      float gh0 = h0[r] + psum[3][b][lr] + bh0;
      float gh1 = h1[r] + psum[4][b][lr] + bh1;
      float gh2 = h2[r] + psum[5][b][lr] + bh2;
      float rr = 1.f/(1.f + expf(-(gx0 + gh0)));
      float zz = 1.f/(1.f + expf(-(gx1 + gh1)));
      float nn = tanhf(gx2 + rr*gh2);
      float hp = hprev[b*1024 + j];
      float hn = (1.f - zz)*nn + zz*hp;
      hout[b*1024 + j] = hn;
      houtb[b*1024 + j] = f2bf(hn);
      if (catb) catb[(long)b*2048 + j] = f2bf(hn);
    }
  }
}

// ---------------- fused decoder attention v3: 64 blocks, per-b 4-slot barrier ----------------
__global__ __launch_bounds__(256) void k_dec_attn3(
    const ushort* __restrict__ h1b, const ushort* __restrict__ memdb,
    float* __restrict__ cov, float* __restrict__ coveS, float* __restrict__ covacc,
    float* __restrict__ scb,
    ushort* __restrict__ ctxn, ushort* __restrict__ catb,
    int* __restrict__ slots, int epoch)
{
  const int bid = blockIdx.x, tid = threadIdx.x;
  const int b = bid >> 2, q = bid & 3;
  const int wv = tid >> 6, lane = tid & 63;
  __shared__ float at[TSN];
  __shared__ float red[256];
  __shared__ float psD[4][64][4];
  float hr[16];
  {
    bf16x8 hv0 = *(const bf16x8*)&h1b[b*1024 + lane*16];
    bf16x8 hv1 = *(const bf16x8*)&h1b[b*1024 + lane*16 + 8];
    #pragma unroll
    for (int e = 0; e < 8; ++e) { hr[e] = bf2f((ushort)hv0[e]); hr[8+e] = bf2f((ushort)hv1[e]); }
  }
  #pragma unroll 2
  for (int i = 0; i < 25; ++i) {
    int t = q*100 + wv*25 + i;
    const ushort* row = memdb + ((long)b*TSN + t)*1024 + lane*16;
    bf16x8 r0 = *(const bf16x8*)row;
    bf16x8 r1 = *(const bf16x8*)(row + 8);
    float p = 0.f;
    #pragma unroll
    for (int e = 0; e < 8; ++e) p += hr[e]*bf2f((ushort)r0[e]) + hr[8+e]*bf2f((ushort)r1[e]);
    #pragma unroll
    for (int off = 32; off; off >>= 1) p += __shfl_xor(p, off);
    if (lane == 0) agat_st((unsigned*)&scb[b*TSN + t], __float_as_uint(p));
  }
  asm volatile("s_waitcnt vmcnt(0)" ::: "memory");
  __syncthreads();
  if (tid == 0) agat_st((unsigned*)(slots + bid*32), (unsigned)epoch);
  if (tid < 4) {
    while ((int)agat_ld((const unsigned*)(slots + (b*4 + tid)*32)) < epoch)
      __builtin_amdgcn_s_sleep(1);
  }
  __syncthreads();
  {
    bool t1v = tid < 144;
    float sc0 = __uint_as_float(agat_ld((const unsigned*)&scb[b*TSN + tid]));
    float sc1 = t1v ? __uint_as_float(agat_ld((const unsigned*)&scb[b*TSN + 256 + tid])) : 0.f;
    float co0 = cov[b*TSN + tid];
    float co1 = t1v ? cov[b*TSN + 256 + tid] : 0.f;
    float ce0 = sc0*(1.f - co0);
    float ce1 = t1v ? sc1*(1.f - co1) : -INFINITY;
    red[tid] = fmaxf(ce0, ce1); __syncthreads();
    for (int o = 128; o; o >>= 1) { if (tid < o) red[tid] = fmaxf(red[tid], red[tid+o]); __syncthreads(); }
    float m = red[0]; __syncthreads();
    float ex0 = expf(ce0 - m), ex1 = t1v ? expf(ce1 - m) : 0.f;
    red[tid] = ex0 + ex1; __syncthreads();
    for (int o = 128; o; o >>= 1) { if (tid < o) red[tid] += red[tid+o]; __syncthreads(); }
    float inv = 1.f/red[0]; __syncthreads();
    float a0 = ex0*inv, a1 = ex1*inv;
    at[tid] = a0;
    if (t1v) at[256 + tid] = a1;
    if (q == 0) {
      coveS[b*TSN + tid] = ce0;
      if (t1v) coveS[b*TSN + 256 + tid] = ce1;
      cov[b*TSN + tid] = co0 + a0;
      if (t1v) cov[b*TSN + 256 + tid] = co1 + a1;
      red[tid] = fminf(a0, co0) + (t1v ? fminf(a1, co1) : 0.f);
      __syncthreads();
      for (int o = 128; o; o >>= 1) { if (tid < o) red[tid] += red[tid+o]; __syncthreads(); }
      if (tid == 0) atomicAdd(covacc, red[0]);
    }
  }
  __syncthreads();
  {
    float acc4[4] = {};
    const int d0 = q*256 + lane*4;
    const unsigned* base = (const unsigned*)memdb + (((long)b*TSN*1024 + d0) >> 1);
    for (int t = wv*100; t < wv*100 + 100; ++t) {
      float a = at[t];
      const unsigned* p = base + (long)t*512;
      unsigned dv0 = p[0], dv1 = p[1];
      acc4[0] += a*bf2f((ushort)(dv0 & 0xffffu));
      acc4[1] += a*bf2f((ushort)(dv0 >> 16));
      acc4[2] += a*bf2f((ushort)(dv1 & 0xffffu));
      acc4[3] += a*bf2f((ushort)(dv1 >> 16));
    }
    #pragma unroll
    for (int e = 0; e < 4; ++e) psD[wv][lane][e] = acc4[e];
    __syncthreads();
    if (wv == 0) {
      float c[4];
      #pragma unroll
      for (int e = 0; e < 4; ++e)
        c[e] = psD[0][lane][e] + psD[1][lane][e] + psD[2][lane][e] + psD[3][lane][e];
      unsigned w0 = (unsigned)f2bf(c[0]) | ((unsigned)f2bf(c[1]) << 16);
      unsigned w1 = (unsigned)f2bf(c[2]) | ((unsigned)f2bf(c[3]) << 16);
      unsigned* cp = (unsigned*)ctxn + ((b*1024 + d0) >> 1);
      cp[0] = w0; cp[1] = w1;
      unsigned* kp = (unsigned*)catb + (((long)b*2048 + 1024 + d0) >> 1);
      kp[0] = w0; kp[1] = w1;
    }
  }
}

// ---------------- hid = tanh(cat @ pW1^T + pb1): 64 blocks x 128 ----------------
__global__ __launch_bounds__(128) void k_hid(
    const ushort* __restrict__ catb, const ushort* __restrict__ W,
    const float* __restrict__ pb1, ushort* __restrict__ hidb)
{
  const int wv = threadIdx.x >> 6;
  const int lane = threadIdx.x & 63;
  const int lr = lane & 15, kg = lane >> 4;
  const int n = blockIdx.x*16 + lr;
  const int kb = wv*1024;
  __shared__ float ps[16][16];
  f32x4 acc = {};
  const ushort* ap = catb + lr*2048 + kb + kg*8;
  const ushort* wp = W + ((long)n << 11) + kb + kg*8;
  #pragma unroll 8
  for (int k0 = 0; k0 < 1024; k0 += 32)
    acc = __builtin_amdgcn_mfma_f32_16x16x32_bf16(*(const bf16x8*)(ap + k0), *(const bf16x8*)(wp + k0), acc, 0, 0, 0);
  if (wv == 1) {
    #pragma unroll
    for (int r = 0; r < 4; ++r) ps[kg*4 + r][lr] = acc[r];
  }
  __syncthreads();
  if (wv == 0) {
    float bv = pb1[n];
    #pragma unroll
    for (int r = 0; r < 4; ++r) {
      int b = kg*4 + r;
      hidb[b*1024 + n] = f2bf(tanhf(acc[r] + ps[b][lr] + bv));
    }
  }
}

// ---------------- batched logits ----------------
__global__ __launch_bounds__(256) void k_logits_all(
    const ushort* __restrict__ hidAll,
    const ushort* __restrict__ pW2b,
    const float* __restrict__ pb2,
    float* __restrict__ outp)
{
  const int wave = threadIdx.x >> 6, lane = threadIdx.x & 63;
  const int lr = lane & 15, kg = lane >> 4;
  const int n0 = blockIdx.x*256 + wave*64;
  const int m0 = blockIdx.y*128;
  f32x4 acc[8][4] = {};
  for (int k0 = 0; k0 < 1024; k0 += 32) {
    bf16x8 bfr[4];
    #pragma unroll
    for (int nt = 0; nt < 4; ++nt)
      bfr[nt] = *(const bf16x8*)&pW2b[(long)(n0 + nt*16 + lr)*1024 + k0 + kg*8];
    #pragma unroll
    for (int mt = 0; mt < 8; ++mt) {
      bf16x8 af = *(const bf16x8*)&hidAll[(long)(m0 + mt*16 + lr)*1024 + k0 + kg*8];
      #pragma unroll
      for (int nt = 0; nt < 4; ++nt)
        acc[mt][nt] = __builtin_amdgcn_mfma_f32_16x16x32_bf16(af, bfr[nt], acc[mt][nt], 0, 0, 0);
    }
  }
  #pragma unroll
  for (int nt = 0; nt < 4; ++nt) {
    int v = n0 + nt*16 + lr;
    if (v >= NEXT) continue;
    float pb = (v < NV) ? pb2[v] : 0.f;
    #pragma unroll
    for (int mt = 0; mt < 8; ++mt) {
      #pragma unroll
      for (int r = 0; r < 4; ++r) {
        int m = m0 + mt*16 + kg*4 + r;
        int s = m >> 4, b = m & 15;
        float e = (v < NV) ? (acc[mt][nt][r] + pb) : 0.f;
        if (e == 0.f) e = NEG_INF;
        outp[((long)b*NTT + s)*NEXT + v] = e;
      }
    }
  }
}

// ---------------- copy-scatter compose ----------------
__device__ __forceinline__ float dec_f(unsigned e) {
  return (e & 0x80000000u) ? __uint_as_float(e ^ 0x80000000u) : __uint_as_float(~e);
}
__global__ __launch_bounds__(512) void k_compose_all(
    const int* __restrict__ ids, const float* __restrict__ coveAll,
    unsigned* __restrict__ ubuf, float* __restrict__ outp)
{
  int b = blockIdx.x, tid = threadIdx.x;
  int v = 0;
  if (tid < TSN) v = ids[b*TSN + tid];
  unsigned* up = ubuf + (long)b*NEXT;
  for (int s = 0; s < NTT; ++s) {
    if (tid < TSN) {
      float ce = coveAll[((long)s*NB + b)*TSN + tid];
      unsigned bb = __float_as_uint(ce);
      unsigned enc = (bb & 0x80000000u) ? ~bb : (bb | 0x80000000u);
      atomicMax(&up[v], enc);
    }
    __syncthreads();
    if (tid < TSN) {
      unsigned u = __hip_atomic_load(&up[v], __ATOMIC_RELAXED, __HIP_MEMORY_SCOPE_AGENT);
      float o = dec_f(u);
      long oi = ((long)b*NTT + s)*NEXT + v;
      float e = outp[oi];
      if (e == NEG_INF) e = 0.f;
      float lg = e + o;
      if (lg == 0.f) lg = NEG_INF;
      outp[oi] = lg;
    }
    __syncthreads();
    if (tid < TSN)
      __hip_atomic_store(&up[v], 0u, __ATOMIC_RELAXED, __HIP_MEMORY_SCOPE_AGENT);
    __syncthreads();
  }
}

// ---------------- final coverage-loss scalar ----------------
__global__ void k_covout(const float* __restrict__ covacc, float* __restrict__ outp)
{
  outp[(long)NB*NTT*NEXT] = covacc[0] * (1.0f/(NB*NTT));
}

// ==================== host ====================
extern "C" void kernel_launch(void* const* d_in, const int* in_sizes, int n_in,
                              void* d_out, int out_size, void* d_ws, size_t ws_size,
                              hipStream_t stream) {
  (void)in_sizes; (void)n_in; (void)out_size; (void)ws_size;
  const float* enc_emb = (const float*)d_in[0];
  const float* ans_emb = (const float*)d_in[1];
  const float* dec_emb = (const float*)d_in[2];
  const float* eWi0 = (const float*)d_in[3];
  const float* eWh0 = (const float*)d_in[4];
  const float* ebi0 = (const float*)d_in[5];
  const float* ebh0 = (const float*)d_in[6];
  const float* eWi1 = (const float*)d_in[7];
  const float* eWh1 = (const float*)d_in[8];
  const float* ebi1 = (const float*)d_in[9];
  const float* ebh1 = (const float*)d_in[10];
  const float* trans_W = (const float*)d_in[11];
  const float* trans_b = (const float*)d_in[12];
  const float* upd_W = (const float*)d_in[13];
  const float* gate_W = (const float*)d_in[14];
  const float* dWi0 = (const float*)d_in[15];
  const float* dWh0 = (const float*)d_in[16];
  const float* dbi0 = (const float*)d_in[17];
  const float* dbh0 = (const float*)d_in[18];
  const float* dWi1 = (const float*)d_in[19];
  const float* dWh1 = (const float*)d_in[20];
  const float* dbi1 = (const float*)d_in[21];
  const float* dbh1 = (const float*)d_in[22];
  const float* dtrans_W = (const float*)d_in[23];
  const float* dtrans_b = (const float*)d_in[24];
  const float* pW1 = (const float*)d_in[25];
  const float* pb1 = (const float*)d_in[26];
  const float* pW2 = (const float*)d_in[27];
  const float* pb2 = (const float*)d_in[28];
  const int* input_s = (const int*)d_in[29];
  const int* ext_ids = (const int*)d_in[30];
  const int* input_q = (const int*)d_in[31];
  const int* input_a = (const int*)d_in[32];
  float* out = (float*)d_out;

  float* ws = (float*)d_ws;
  size_t off = 0;
  auto alloc = [&](size_t n) { float* p = ws + off; off += (n + 15) & ~(size_t)15; return p; };
  auto alloch = [&](size_t nh) { return (ushort*)alloc((nh + 1) / 2); };

  // --- small persistent ---
  ushort* hpp  = alloch(2ull*2*NB*HENC);
  int*   bar   = (int*)alloc(4096);
  float* covacc= alloc(4);
  float* cov   = alloc(NB*TSN);
  float* scb   = alloc(NB*TSN);
  unsigned* ubuf = (unsigned*)alloc((size_t)NB*NEXT);
  float* hfin0 = alloc(NB*HD2);
  float* hfin1 = alloc(NB*HD2);
  float* dh0   = alloc(2ull*NB*HD2);
  float* dh1   = alloc(2ull*NB*HD2);
  ushort* h0b  = alloch(2ull*NB*HD2);
  ushort* h1b  = alloch(2ull*NB*HD2);
  ushort* ctxbf= alloch(2ull*NB*HD2);
  ushort* catbf= alloch((size_t)NB*2048);
  ushort* hidAll = alloch((size_t)NTT*NB*HD2);
  float* coveAll = alloc((size_t)NTT*NB*TSN);

  // --- bf16 weights ---
  ushort* eWi0c   = alloch(2ull*G3E*384);
  ushort* eWi1c   = alloch(2ull*G3E*1024);
  ushort* Whb0    = alloch(2ull*G3E*HENC);
  ushort* Whb1    = alloch(2ull*G3E*HENC);
  ushort* transWb = alloch(1024ull*1024);
  ushort* fgWb    = alloch(2048ull*2048);
  ushort* dtransWb= alloch(1024ull*1024);
  ushort* dWi0e   = alloch(3072ull*320);
  ushort* dWi0c   = alloch(3072ull*1024);
  ushort* dWh0b   = alloch(3072ull*1024);
  ushort* dWi1b   = alloch(3072ull*1024);
  ushort* dWh1b   = alloch(3072ull*1024);
  ushort* pW1b    = alloch(1024ull*2048);

  // --- alias region: [GX(bf16) | X0c | Y0bf | pad] -> later ftgt_bf, then pW2b ---
  size_t regionStart = off;
  float*  GXr  = alloc(2ull*6400*G3E);
  ushort* GXbf = (ushort*)GXr;
  ushort* X0c  = alloch(6400ull*384);
  ushort* Y0bf = alloch(6400ull*1024);
  alloc(6400ull*HD2);
  ushort* ftgt_bf = (ushort*)(ws + regionStart);
  ushort* pW2b    = (ushort*)(ws + regionStart);
  ushort* outpTb  = (ushort*)(ws + regionStart + 26000000);

  // --- big buffers ---
  ushort* memsbf = alloch(6400ull*HD2);
  ushort* catE   = alloch(6400ull*2048);     // [6400][2048] = [enc_out | ctx]
  float*  energ  = alloc((size_t)NB*TSN*TSN);
  ushort* scoresb= alloch((size_t)NB*TSN*448);
  ushort* memd_bf= alloch(6400ull*HD2);
  ushort* encbf  = alloch(6400ull*HD2);
  ushort* embqb  = alloch(512ull*320);
  float*  embGX  = alloc(512ull*G3D);

  // ---------------- one-time casts ----------------
  k_embed_bf<<<9600, 256, 0, stream>>>(enc_emb, ans_emb, input_s, input_a, X0c);
  k_castw<<<4608, 256, 0, stream>>>(eWi0, eWi0c, 3072, 3072ull*384, 332, 384, 332, 0);
  {
    CJobs jobs;
    jobs.nj = 11;
    jobs.j[0]  = { (const float4*)eWi1,    eWi1c,               393216 };
    jobs.j[1]  = { (const float4*)eWh0,    Whb0,                196608 };
    jobs.j[2]  = { (const float4*)eWh1,    Whb1,                196608 };
    jobs.j[3]  = { (const float4*)trans_W, transWb,             131072 };
    jobs.j[4]  = { (const float4*)upd_W,   fgWb,                262144 };
    jobs.j[5]  = { (const float4*)gate_W,  fgWb + 1024ull*2048, 262144 };
    jobs.j[6]  = { (const float4*)dtrans_W, dtransWb,           131072 };
    jobs.j[7]  = { (const float4*)dWh0,    dWh0b,               393216 };
    jobs.j[8]  = { (const float4*)dWi1,    dWi1b,               393216 };
    jobs.j[9]  = { (const float4*)dWh1,    dWh1b,               393216 };
    jobs.j[10] = { (const float4*)pW1,     pW1b,                262144 };
    k_cast8_multi<<<2048, 256, 0, stream>>>(jobs);
  }
  k_castw<<<3840, 256, 0, stream>>>(dWi0, dWi0e, 3072, 3072ull*320, 300, 320, 1324, 0);
  k_castw<<<12288, 256, 0, stream>>>(dWi0, dWi0c, 3072, 3072ull*1024, 1024, 1024, 1324, 300);

  hipMemsetAsync(bar, 0, 16384, stream);

  // ---------------- encoder layer 0 ----------------
  k_mfma128<<<dim3(50,12,2), 256, 0, stream>>>(X0c, eWi0c, ebi0, GXbf,
      384, 384, 384, G3E, 0, (long)G3E*384, 6400ull*G3E, G3E);
  hipMemsetAsync(hpp, 0, 2ull*2*NB*HENC*2, stream);
  k_scan_mfma<<<121, 256, 0, stream>>>(GXbf, GXbf + 6400ull*G3E, Whb0, ebh0,
      Y0bf, 0, 1024, hfin0, hpp, bar);
  // ---------------- encoder layer 1 (writes catE lower half directly) ----------------
  k_mfma128<<<dim3(50,12,2), 256, 0, stream>>>(Y0bf, eWi1c, ebi1, GXbf,
      1024, 1024, 1024, G3E, 0, (long)G3E*1024, 6400ull*G3E, G3E);
  hipMemsetAsync(hpp, 0, 2ull*2*NB*HENC*2, stream);
  k_scan_mfma<<<121, 256, 0, stream>>>(GXbf, GXbf + 6400ull*G3E, Whb1, ebh1,
      catE, 1, 2048, hfin1, hpp, bar + 512);

  // ---------------- self/answer attention ----------------
  k_mfma128<<<dim3(50,8,1), 256, 0, stream>>>(catE, transWb, trans_b, memsbf,
      1024, 2048, 1024, 1024, 0, 0, 0, 0);
  k_mfma_nt<<<dim3(7,7,16), 256, 0, stream>>>(catE, memsbf, nullptr, energ, nullptr,
      TSN, TSN, 1024, 2048, 1024, TSN, (long)TSN*2048, (long)TSN*1024, (long)TSN*TSN, 0, 0, 0);
  k_softmax_bf<<<NB*TSN, 256, 0, stream>>>(energ, scoresb);
  k_transpose_hh<<<dim3(14,32,16), 256, 0, stream>>>(catE, outpTb, 2048);
  k_mfma_nt<<<dim3(7,16,16), 256, 0, stream>>>(scoresb, outpTb, nullptr, nullptr, catE + 1024,
      TSN, HD2, 448, 448, 448, 2048, (long)TSN*448, (long)HD2*448, (long)TSN*2048, 0, 0, 0);
  k_mfma128<<<dim3(50,16,1), 256, 0, stream>>>(catE, fgWb, nullptr, ftgt_bf,
      2048, 2048, 2048, 2048, 0, 0, 0, 0);
  k_ansatt2<<<64, 256, 0, stream>>>(memsbf, ftgt_bf, catE, input_a, encbf);
  // region dead after ansatt2: cast pW2 over it (vectorized) + zero pad rows
  k_cast8<<<25000, 256, 0, stream>>>((const float4*)pW2, pW2b, 6400000);
  hipMemsetAsync(pW2b + 50000l*1024, 0, 176l*1024*2, stream);
  k_mfma128<<<dim3(50,8,1), 256, 0, stream>>>(encbf, dtransWb, dtrans_b, memd_bf,
      1024, 1024, 1024, 1024, 0, 0, 0, 0);

  // ---------------- decoder precompute ----------------
  k_embq_bf<<<640, 256, 0, stream>>>(dec_emb, input_q, embqb);
  k_mfma_nt<<<dim3(8,48,1), 256, 0, stream>>>(embqb, dWi0e, dbi0, embGX, nullptr,
      NTT*NB, G3D, 320, 320, 320, G3D, 0, 0, 0, 0, 0, 0);

  hipMemsetAsync(cov, 0, (size_t)NB*TSN*4, stream);
  hipMemsetAsync(covacc, 0, 4, stream);
  hipMemsetAsync(ubuf, 0, (size_t)NB*NEXT*4, stream);
  hipMemsetAsync(ctxbf, 0, (size_t)NB*HD2*2, stream);
  hipMemcpyAsync(dh0, hfin0, (size_t)NB*HD2*4, hipMemcpyDeviceToDevice, stream);
  hipMemcpyAsync(dh1, hfin1, (size_t)NB*HD2*4, hipMemcpyDeviceToDevice, stream);
  k_cast<<<64, 256, 0, stream>>>(hfin0, h0b, 16384);
  k_cast<<<64, 256, 0, stream>>>(hfin1, h1b, 16384);

  // ---------------- decoder steps ----------------
  for (int s = 0; s < NTT; ++s) {
    int cur = s & 1, nxt = cur ^ 1;
    float* h0c = dh0 + (size_t)cur*NB*HD2;  float* h0n = dh0 + (size_t)nxt*NB*HD2;
    float* h1c = dh1 + (size_t)cur*NB*HD2;  float* h1n = dh1 + (size_t)nxt*NB*HD2;
    ushort* h0bc = h0b + (size_t)cur*NB*HD2; ushort* h0bn = h0b + (size_t)nxt*NB*HD2;
    ushort* h1bc = h1b + (size_t)cur*NB*HD2; ushort* h1bn = h1b + (size_t)nxt*NB*HD2;
    ushort* ctxc = ctxbf + (size_t)cur*NB*HD2; ushort* ctxn = ctxbf + (size_t)nxt*NB*HD2;

    k_gru_dec<<<64, 128, 0, stream>>>(ctxc, dWi0c, h0bc, dWh0b,
        embGX + (size_t)s*NB*G3D, nullptr, dbh0, h0c, h0n, h0bn, nullptr);
    k_gru_dec<<<64, 128, 0, stream>>>(h0bn, dWi1b, h1bc, dWh1b,
        nullptr, dbi1, dbh1, h1c, h1n, h1bn, catbf);
    k_dec_attn3<<<64, 256, 0, stream>>>(h1bn, memd_bf,
        cov, coveAll + (size_t)s*NB*TSN, covacc, scb, ctxn, catbf,
        bar + 1024, s + 1);
    k_hid<<<64, 128, 0, stream>>>(catbf, pW1b, pb1, hidAll + (size_t)s*NB*HD2);
  }
  // ---------------- batched logits + compose ----------------
  k_logits_all<<<dim3(196, 4), 256, 0, stream>>>(hidAll, pW2b, pb2, out);
  k_compose_all<<<NB, 512, 0, stream>>>(ext_ids, coveAll, ubuf, out);
  k_covout<<<1, 1, 0, stream>>>(covacc, out);
}

// Round 19
// 4932.727 us; speedup vs baseline: 1.2181x; 1.1474x over previous
//
#include <hip/hip_runtime.h>
#include <stdint.h>

#define TSN 400
#define NB 16
#define HENC 512
#define HD2 1024
#define G3E 1536
#define G3D 3072
#define EMBD 300
#define AEMB 32
#define NV 50000
#define NEXT 50100
#define NVP 50176
#define NTT 32
#define NEG_INF (-1.0e12f)

typedef __attribute__((ext_vector_type(8))) short bf16x8;
typedef __attribute__((ext_vector_type(4))) float f32x4;

struct CJob { const float4* s; ushort* d; long n8; };
struct CJobs { CJob j[12]; int nj; };

__device__ __forceinline__ ushort f2bf(float f) {
  unsigned u = __float_as_uint(f);
  unsigned r = (u + 0x7fffu + ((u >> 16) & 1u)) >> 16;
  return (ushort)r;
}
__device__ __forceinline__ float bf2f(ushort h) {
  return __uint_as_float((unsigned)h << 16);
}
__device__ __forceinline__ unsigned agat_ld(const unsigned* p) {
  return __hip_atomic_load(p, __ATOMIC_RELAXED, __HIP_MEMORY_SCOPE_AGENT);
}
__device__ __forceinline__ void agat_st(unsigned* p, unsigned v) {
  __hip_atomic_store(p, v, __ATOMIC_RELAXED, __HIP_MEMORY_SCOPE_AGENT);
}
__device__ __forceinline__ unsigned long long agat_ld64(const unsigned long long* p) {
  return __hip_atomic_load(p, __ATOMIC_RELAXED, __HIP_MEMORY_SCOPE_AGENT);
}
// fast sigmoid/tanh: v_exp + v_rcp (1-2 ulp; bf16 rounding dominates downstream)
__device__ __forceinline__ float fsig(float x) {
  return __builtin_amdgcn_rcpf(1.f + __expf(-x));
}
__device__ __forceinline__ float ftanh(float x) {
  float t = __expf(-2.f*fabsf(x));           // t in (0,1], no inf
  float r = (1.f - t)*__builtin_amdgcn_rcpf(1.f + t);
  return copysignf(r, x);
}

// ---------------- embeddings -> bf16, padded K=384 ----------------
__global__ __launch_bounds__(256) void k_embed_bf(
    const float* __restrict__ enc_emb, const float* __restrict__ ans_emb,
    const int* __restrict__ input_s, const int* __restrict__ input_a,
    ushort* __restrict__ X0)
{
  long i = (long)blockIdx.x*256 + threadIdx.x;
  if (i >= (long)TSN*NB*384) return;
  int c = (int)(i % 384);
  long r = i / 384;
  int b = (int)(r % NB);
  int t = (int)(r / NB);
  float v = 0.f;
  if (c < EMBD) v = enc_emb[(long)input_s[b*TSN + t]*EMBD + c];
  else if (c < 332) v = ans_emb[(long)input_a[b*TSN + t]*AEMB + (c - EMBD)];
  X0[i] = f2bf(v);
}

// ---------------- decoder emb -> bf16, padded K=320 ----------------
__global__ __launch_bounds__(256) void k_embq_bf(
    const float* __restrict__ dec_emb, const int* __restrict__ input_q,
    ushort* __restrict__ EQ)
{
  long i = (long)blockIdx.x*256 + threadIdx.x;
  if (i >= (long)NTT*NB*320) return;
  int c = (int)(i % 320);
  long r = i / 320;
  int b = (int)(r % NB);
  int s = (int)(r / NB);
  EQ[i] = (c < EMBD) ? f2bf(dec_emb[(long)input_q[b*33 + s]*EMBD + c]) : (ushort)0;
}

// ---------------- weight cast with pad (strided / padded cases) ----------------
__global__ __launch_bounds__(256) void k_castw(
    const float* __restrict__ src, ushort* __restrict__ dst,
    int Nsrc, long total, int Ksrc, int Kdst, int ldsrc, int coloff)
{
  long i = (long)blockIdx.x*256 + threadIdx.x;
  if (i >= total) return;
  int k = (int)(i % Kdst);
  long n = i / Kdst;
  float v = (n < Nsrc && k < Ksrc) ? src[n*ldsrc + coloff + k] : 0.f;
  dst[i] = f2bf(v);
}

// ---------------- vectorized contiguous cast ----------------
__global__ __launch_bounds__(256) void k_cast8(
    const float4* __restrict__ s, ushort* __restrict__ d, long n8)
{
  long i = (long)blockIdx.x*256 + threadIdx.x;
  if (i >= n8) return;
  float4 v0 = s[2*i], v1 = s[2*i + 1];
  union { ushort u[8]; bf16x8 h; } c;
  c.u[0] = f2bf(v0.x); c.u[1] = f2bf(v0.y); c.u[2] = f2bf(v0.z); c.u[3] = f2bf(v0.w);
  c.u[4] = f2bf(v1.x); c.u[5] = f2bf(v1.y); c.u[6] = f2bf(v1.z); c.u[7] = f2bf(v1.w);
  *(bf16x8*)&d[i*8] = c.h;
}

// ---------------- multi-job contiguous cast (one launch) ----------------
__global__ __launch_bounds__(256) void k_cast8_multi(CJobs jobs)
{
  const long stride = (long)gridDim.x*256;
  for (int ji = 0; ji < jobs.nj; ++ji) {
    const float4* s = jobs.j[ji].s;
    ushort* d = jobs.j[ji].d;
    const long n8 = jobs.j[ji].n8;
    for (long i = (long)blockIdx.x*256 + threadIdx.x; i < n8; i += stride) {
      float4 v0 = s[2*i], v1 = s[2*i + 1];
      union { ushort u[8]; bf16x8 h; } c;
      c.u[0] = f2bf(v0.x); c.u[1] = f2bf(v0.y); c.u[2] = f2bf(v0.z); c.u[3] = f2bf(v0.w);
      c.u[4] = f2bf(v1.x); c.u[5] = f2bf(v1.y); c.u[6] = f2bf(v1.z); c.u[7] = f2bf(v1.w);
      *(bf16x8*)&d[i*8] = c.h;
    }
  }
}

// ---------------- plain cast fp32 -> bf16 ----------------
__global__ __launch_bounds__(256) void k_cast(
    const float* __restrict__ s, ushort* __restrict__ d, long n)
{
  long i = (long)blockIdx.x*256 + threadIdx.x;
  if (i >= n) return;
  d[i] = f2bf(s[i]);
}

// ---------------- bf16 batched transpose with K-pad: out[b][c][r(448)] ----------------
__global__ __launch_bounds__(256) void k_transpose_hh(
    const ushort* __restrict__ in, ushort* __restrict__ out, int ldin)
{
  __shared__ ushort tb[32][33];
  int b = blockIdx.z;
  int r0 = blockIdx.x*32, c0 = blockIdx.y*32;
  int tx = threadIdx.x & 31, ty = threadIdx.x >> 5;
  #pragma unroll
  for (int i = 0; i < 32; i += 8) {
    int r = r0 + ty + i, c = c0 + tx;
    tb[ty+i][tx] = (r < TSN) ? in[((long)b*TSN + r)*ldin + c] : (ushort)0;
  }
  __syncthreads();
  #pragma unroll
  for (int i = 0; i < 32; i += 8) {
    int c = c0 + ty + i, r = r0 + tx;
    out[((long)b*1024 + c)*448 + r] = tb[tx][ty+i];
  }
}

// ---------------- MFMA GEMM 64x64 (fp32 C optional; bf16 C2 optional) ----------------
__global__ __launch_bounds__(256) void k_mfma_nt(
    const ushort* __restrict__ Ab, const ushort* __restrict__ Wb,
    const float* __restrict__ bias, float* __restrict__ Cb, ushort* __restrict__ C2b,
    int M, int N, int K, int lda, int ldw, int ldc,
    long sA, long sW, long sC, long sBias, int accum, int act)
{
  __shared__ ushort As[64][72];
  __shared__ ushort Ws[64][72];
  const ushort* A = Ab + (long)blockIdx.z * sA;
  const ushort* W = Wb + (long)blockIdx.z * sW;
  float* C = Cb ? Cb + (long)blockIdx.z * sC : nullptr;
  const float* bi = bias ? bias + (long)blockIdx.z * sBias : nullptr;
  const int m0 = blockIdx.x*64, n0 = blockIdx.y*64;
  const int tid = threadIdx.x;
  const int wave = tid >> 6, lane = tid & 63;
  const int wm = wave >> 1, wn = wave & 1;
  const int lr = lane & 15, kg = lane >> 4;
  f32x4 acc[2][2] = {};
  for (int k0 = 0; k0 < K; k0 += 64) {
    __syncthreads();
    #pragma unroll
    for (int it = 0; it < 2; ++it) {
      int sidx = tid + it*256;
      int r = sidx >> 3, c = (sidx & 7)*8;
      bf16x8 av = {};
      bf16x8 wv = {};
      if (m0 + r < M) av = *(const bf16x8*)&A[(long)(m0+r)*lda + k0 + c];
      if (n0 + r < N) wv = *(const bf16x8*)&W[(long)(n0+r)*ldw + k0 + c];
      *(bf16x8*)&As[r][c] = av;
      *(bf16x8*)&Ws[r][c] = wv;
    }
    __syncthreads();
    #pragma unroll
    for (int kk = 0; kk < 2; ++kk) {
      bf16x8 af[2], bf[2];
      #pragma unroll
      for (int mt = 0; mt < 2; ++mt)
        af[mt] = *(const bf16x8*)&As[wm*32 + mt*16 + lr][kk*32 + kg*8];
      #pragma unroll
      for (int nt = 0; nt < 2; ++nt)
        bf[nt] = *(const bf16x8*)&Ws[wn*32 + nt*16 + lr][kk*32 + kg*8];
      #pragma unroll
      for (int mt = 0; mt < 2; ++mt)
        #pragma unroll
        for (int nt = 0; nt < 2; ++nt)
          acc[mt][nt] = __builtin_amdgcn_mfma_f32_16x16x32_bf16(af[mt], bf[nt], acc[mt][nt], 0, 0, 0);
    }
  }
  #pragma unroll
  for (int mt = 0; mt < 2; ++mt) {
    #pragma unroll
    for (int r = 0; r < 4; ++r) {
      int m = m0 + wm*32 + mt*16 + kg*4 + r;
      if (m >= M) continue;
      #pragma unroll
      for (int nt = 0; nt < 2; ++nt) {
        int n = n0 + wn*32 + nt*16 + lr;
        if (n >= N) continue;
        float v = acc[mt][nt][r];
        if (accum && C) v += C[(long)m*ldc + n];
        if (bi)    v += bi[n];
        if (act == 1) v = ftanh(v);
        else if (act == 2) v = fsig(v);
        if (C) C[(long)m*ldc + n] = v;
        if (C2b) C2b[(long)blockIdx.z*sC + (long)m*ldc + n] = f2bf(v);
      }
    }
  }
}

// ---------------- MFMA GEMM 128x128 (guard-free, bias optional, bf16 out) ----------------
__global__ __launch_bounds__(256) void k_mfma128(
    const ushort* __restrict__ Ab, const ushort* __restrict__ Wb,
    const float* __restrict__ bias, ushort* __restrict__ C2b,
    int K, int lda, int ldw, int ldc,
    long sA, long sW, long sC, long sBias)
{
  __shared__ ushort As[128][72];
  __shared__ ushort Ws[128][72];
  const ushort* A = Ab + (long)blockIdx.z * sA;
  const ushort* W = Wb + (long)blockIdx.z * sW;
  ushort* C2 = C2b + (long)blockIdx.z * sC;
  const float* bi = bias ? bias + (long)blockIdx.z * sBias : nullptr;
  const int m0 = blockIdx.x*128, n0 = blockIdx.y*128;
  const int tid = threadIdx.x;
  const int wave = tid >> 6, lane = tid & 63;
  const int wm = wave >> 1, wn = wave & 1;
  const int lr = lane & 15, kg = lane >> 4;
  f32x4 acc[4][4] = {};
  for (int k0 = 0; k0 < K; k0 += 64) {
    __syncthreads();
    #pragma unroll
    for (int it = 0; it < 4; ++it) {
      int idx = it*256 + tid;
      int r = idx >> 3, c = (idx & 7)*8;
      *(bf16x8*)&As[r][c] = *(const bf16x8*)&A[(long)(m0+r)*lda + k0 + c];
      *(bf16x8*)&Ws[r][c] = *(const bf16x8*)&W[(long)(n0+r)*ldw + k0 + c];
    }
    __syncthreads();
    #pragma unroll
    for (int kk = 0; kk < 2; ++kk) {
      bf16x8 af[4], bfv[4];
      #pragma unroll
      for (int mt = 0; mt < 4; ++mt)
        af[mt] = *(const bf16x8*)&As[wm*64 + mt*16 + lr][kk*32 + kg*8];
      #pragma unroll
      for (int nt = 0; nt < 4; ++nt)
        bfv[nt] = *(const bf16x8*)&Ws[wn*64 + nt*16 + lr][kk*32 + kg*8];
      #pragma unroll
      for (int mt = 0; mt < 4; ++mt)
        #pragma unroll
        for (int nt = 0; nt < 4; ++nt)
          acc[mt][nt] = __builtin_amdgcn_mfma_f32_16x16x32_bf16(af[mt], bfv[nt], acc[mt][nt], 0, 0, 0);
    }
  }
  #pragma unroll
  for (int mt = 0; mt < 4; ++mt) {
    #pragma unroll
    for (int r = 0; r < 4; ++r) {
      int m = m0 + wm*64 + mt*16 + kg*4 + r;
      #pragma unroll
      for (int nt = 0; nt < 4; ++nt) {
        int n = n0 + wn*64 + nt*16 + lr;
        float v = acc[mt][nt][r];
        if (bi) v += bi[n];
        C2[(long)m*ldc + n] = f2bf(v);
      }
    }
  }
}

// ---------------- persistent MFMA bidirectional GRU scan v6 + XCD-local remap ----------------
__global__ __launch_bounds__(256, 1) void k_scan_mfma(
    const ushort* __restrict__ GXf, const ushort* __restrict__ GXb,
    const ushort* __restrict__ Whb,
    const float* __restrict__ bh,
    ushort* __restrict__ Ybf, int bmajor, int ldY,
    float* __restrict__ hfin,
    ushort* __restrict__ hpp,
    int* __restrict__ slots)
{
  const int bidx = blockIdx.x;
  if (bidx & 7) return;
  const int sid = bidx >> 3;          // 0..15
  const int tid = threadIdx.x;
  const int wg = sid*4 + (tid >> 6);
  const int lane = tid & 63;
  const int lr = lane & 15, kg = lane >> 4;
  const int dir = wg >> 5, jt = wg & 31;
  const int j = jt*16 + lr;
  __shared__ ushort hsm[16][520];
  const ushort* Wp0 = Whb + ((long)(dir*G3E + j)        << 9) + kg*8;
  const ushort* Wp1 = Whb + ((long)(dir*G3E + 512 + j)  << 9) + kg*8;
  const ushort* Wp2 = Whb + ((long)(dir*G3E + 1024 + j) << 9) + kg*8;
  bf16x8 W0[16], W1[16], W2[16];
  #pragma unroll
  for (int i = 0; i < 16; ++i) {
    W0[i] = *(const bf16x8*)(Wp0 + i*32);
    W1[i] = *(const bf16x8*)(Wp1 + i*32);
    W2[i] = *(const bf16x8*)(Wp2 + i*32);
  }
  const float bh0 = bh[dir*G3E + j];
  const float bh1 = bh[dir*G3E + 512 + j];
  const float bh2 = bh[dir*G3E + 1024 + j];
  const ushort* GX = dir ? GXb : GXf;
  unsigned* hppu = (unsigned*)hpp;
  int* myslot = slots + dir*256 + (sid & 7)*32;
  int* dslots = slots + dir*256;
  float hreg[4] = {0.f, 0.f, 0.f, 0.f};
  float g0[4], g1[4], g2[4];
  {
    const int t0 = dir ? (TSN - 1) : 0;
    const ushort* gxp = GX + (long)t0*NB*G3E + j;
    #pragma unroll
    for (int r = 0; r < 4; ++r) {
      const ushort* g = gxp + (long)(kg*4 + r)*G3E;
      g0[r] = bf2f(g[0]); g1[r] = bf2f(g[512]); g2[r] = bf2f(g[1024]);
    }
  }
  for (int s = 0; s < TSN; ++s) {
    const int cur = s & 1;
    {
      const unsigned long long* hin =
          (const unsigned long long*)hppu + (cur*2 + dir)*2048;
      unsigned long long vqw[8];
      #pragma unroll
      for (int i = 0; i < 8; ++i) vqw[i] = agat_ld64(hin + i*256 + tid);
      #pragma unroll
      for (int i = 0; i < 8; ++i) {
        int d0 = 2*(i*256 + tid);
        *(unsigned long long*)&hsm[d0 >> 8][(d0 & 255)*2] = vqw[i];
      }
    }
    __syncthreads();
    f32x4 a0 = {}, a1 = {}, a2 = {};
    #pragma unroll
    for (int i = 0; i < 16; ++i) {
      bf16x8 hf = *(const bf16x8*)&hsm[lr][kg*8 + i*32];
      a0 = __builtin_amdgcn_mfma_f32_16x16x32_bf16(hf, W0[i], a0, 0, 0, 0);
      a1 = __builtin_amdgcn_mfma_f32_16x16x32_bf16(hf, W1[i], a1, 0, 0, 0);
      a2 = __builtin_amdgcn_mfma_f32_16x16x32_bf16(hf, W2[i], a2, 0, 0, 0);
    }
    const int t = dir ? (TSN - 1 - s) : s;
    const int obase = ((cur^1)*2 + dir)*16*512;
    float hsave[4];
    #pragma unroll
    for (int r = 0; r < 4; ++r) {
      int b = kg*4 + r;
      float rr = fsig(g0[r] + a0[r] + bh0);
      float zz = fsig(g1[r] + a1[r] + bh1);
      float nn = ftanh(g2[r] + rr*(a2[r] + bh2));
      float hn = (1.f - zz)*nn + zz*hreg[r];
      hreg[r] = hn;
      hsave[r] = hn;
      unsigned hv = f2bf(hn);
      unsigned pv = (unsigned)__shfl_xor((int)hv, 1);
      if ((lr & 1) == 0)
        agat_st(hppu + ((obase + b*512 + j) >> 1), hv | (pv << 16));
    }
    if (s + 1 < TSN) {
      asm volatile("s_waitcnt vmcnt(0)" ::: "memory");
      __syncthreads();
      if (tid == 0)
        agat_st((unsigned*)myslot, (unsigned)(s + 1));
      {
        const int tn = dir ? (TSN - 2 - s) : (s + 1);
        const ushort* gxp = GX + (long)tn*NB*G3E + j;
        #pragma unroll
        for (int r = 0; r < 4; ++r) {
          const ushort* g = gxp + (long)(kg*4 + r)*G3E;
          g0[r] = bf2f(g[0]); g1[r] = bf2f(g[512]); g2[r] = bf2f(g[1024]);
        }
      }
      #pragma unroll
      for (int r = 0; r < 4; ++r) {
        int b = kg*4 + r;
        long yi = bmajor ? ((long)b*TSN + t)*ldY + dir*512 + j
                         : ((long)t*NB + b)*1024 + dir*512 + j;
        Ybf[yi] = f2bf(hsave[r]);
      }
      if (tid < 8) {
        while ((int)agat_ld((const unsigned*)(dslots + tid*32)) < s + 1)
          __builtin_amdgcn_s_sleep(1);
      }
      __syncthreads();
    } else {
      #pragma unroll
      for (int r = 0; r < 4; ++r) {
        int b = kg*4 + r;
        long yi = bmajor ? ((long)b*TSN + t)*ldY + dir*512 + j
                         : ((long)t*NB + b)*1024 + dir*512 + j;
        Ybf[yi] = f2bf(hsave[r]);
        hfin[b*1024 + dir*512 + j] = hsave[r];
      }
    }
  }
}

// ---------------- row softmax f32 -> bf16 (pad to 448) ----------------
__global__ __launch_bounds__(256) void k_softmax_bf(
    const float* __restrict__ E, ushort* __restrict__ S)
{
  long row = blockIdx.x;
  const float* x = E + row*TSN;
  ushort* o = S + row*448;
  int tid = threadIdx.x;
  float v0 = (tid < TSN) ? x[tid] : -INFINITY;
  float v1 = (tid + 256 < TSN) ? x[tid + 256] : -INFINITY;
  __shared__ float red[256];
  red[tid] = fmaxf(v0, v1); __syncthreads();
  for (int oo = 128; oo; oo >>= 1) { if (tid < oo) red[tid] = fmaxf(red[tid], red[tid+oo]); __syncthreads(); }
  float m = red[0]; __syncthreads();
  float e0 = (tid < TSN) ? __expf(v0 - m) : 0.f;
  float e1 = (tid + 256 < TSN) ? __expf(v1 - m) : 0.f;
  red[tid] = e0 + e1; __syncthreads();
  for (int oo = 128; oo; oo >>= 1) { if (tid < oo) red[tid] += red[tid+oo]; __syncthreads(); }
  float inv = 1.f/red[0];
  if (tid < 192) o[tid + 256] = (tid + 256 < TSN) ? f2bf(e1*inv) : (ushort)0;
  o[tid] = f2bf(e0*inv);
}

// ---------------- fused selfcomb (raw preacts) + answer attention -> encbf ----------------
__global__ __launch_bounds__(256) void k_ansatt2(
    const ushort* __restrict__ memsb, const ushort* __restrict__ ftgt,
    const ushort* __restrict__ outpb,   // stride 2048 (catE lower half)
    const int* __restrict__ input_a, ushort* __restrict__ encb)
{
  int b = blockIdx.x >> 2;
  int d = (blockIdx.x & 3)*256 + threadIdx.x;
  __shared__ int ia[TSN];
  for (int i = threadIdx.x; i < TSN; i += 256) ia[i] = input_a[b*TSN + i];
  __syncthreads();
  float m = -INFINITY;
  #pragma unroll 4
  for (int t = 0; t < TSN; ++t) {
    float v = bf2f(memsb[((long)b*TSN + t)*1024 + d]);
    float e = ia[t] ? v*v : v;
    m = fmaxf(m, e);
  }
  float ssum = 0.f;
  #pragma unroll 4
  for (int t = 0; t < TSN; ++t) {
    float v = bf2f(memsb[((long)b*TSN + t)*1024 + d]);
    float e = ia[t] ? v*v : v;
    ssum += __expf(e - m);
  }
  float inv = 1.f/ssum;
  #pragma unroll 4
  for (int t = 0; t < TSN; ++t) {
    long idx = ((long)b*TSN + t)*1024 + d;
    long idx2 = ((long)b*TSN + t)*2048 + d;
    float v = bf2f(memsb[idx]);
    float e = ia[t] ? v*v : v;
    float fraw = bf2f(ftgt[idx2]);
    float graw = bf2f(ftgt[idx2 + 1024]);
    float gg = fsig(graw);
    float selfo = gg*ftanh(fraw) + (1.f - gg)*bf2f(outpb[idx2]);
    encb[idx] = f2bf(selfo + __expf(e - m)*inv*v);
  }
}

// ---------------- decoder GRU layer: 64 blocks x 128 (2 waves split K) ----------------
__global__ __launch_bounds__(128) void k_gru_dec(
    const ushort* __restrict__ A1, const ushort* __restrict__ W1,
    const ushort* __restrict__ A2, const ushort* __restrict__ W2,
    const float* __restrict__ gxadd, const float* __restrict__ bi,
    const float* __restrict__ bh,
    const float* __restrict__ hprev, float* __restrict__ hout,
    ushort* __restrict__ houtb, ushort* __restrict__ catb)
{
  const int wv = threadIdx.x >> 6;
  const int lane = threadIdx.x & 63;
  const int lr = lane & 15, kg = lane >> 4;
  const int j = blockIdx.x*16 + lr;
  const int kb = wv*512;
  __shared__ float psum[6][16][16];
  const ushort* w1p0 = W1 + ((long)(j)        << 10) + kb + kg*8;
  const ushort* w1p1 = W1 + ((long)(1024 + j) << 10) + kb + kg*8;
  const ushort* w1p2 = W1 + ((long)(2048 + j) << 10) + kb + kg*8;
  const ushort* w2p0 = W2 + ((long)(j)        << 10) + kb + kg*8;
  const ushort* w2p1 = W2 + ((long)(1024 + j) << 10) + kb + kg*8;
  const ushort* w2p2 = W2 + ((long)(2048 + j) << 10) + kb + kg*8;
  const ushort* a1p = A1 + lr*1024 + kb + kg*8;
  const ushort* a2p = A2 + lr*1024 + kb + kg*8;
  f32x4 x0 = {}, x1 = {}, x2 = {}, h0 = {}, h1 = {}, h2 = {};
  #pragma unroll 4
  for (int k0 = 0; k0 < 512; k0 += 32) {
    bf16x8 a1v = *(const bf16x8*)(a1p + k0);
    bf16x8 a2v = *(const bf16x8*)(a2p + k0);
    x0 = __builtin_amdgcn_mfma_f32_16x16x32_bf16(a1v, *(const bf16x8*)(w1p0 + k0), x0, 0, 0, 0);
    x1 = __builtin_amdgcn_mfma_f32_16x16x32_bf16(a1v, *(const bf16x8*)(w1p1 + k0), x1, 0, 0, 0);
    x2 = __builtin_amdgcn_mfma_f32_16x16x32_bf16(a1v, *(const bf16x8*)(w1p2 + k0), x2, 0, 0, 0);
    h0 = __builtin_amdgcn_mfma_f32_16x16x32_bf16(a2v, *(const bf16x8*)(w2p0 + k0), h0, 0, 0, 0);
    h1 = __builtin_amdgcn_mfma_f32_16x16x32_bf16(a2v, *(const bf16x8*)(w2p1 + k0), h1, 0, 0, 0);
    h2 = __builtin_amdgcn_mfma_f32_16x16x32_bf16(a2v, *(const bf16x8*)(w2p2 + k0), h2, 0, 0, 0);
  }
  if (wv == 1) {
    #pragma unroll
    for (int r = 0; r < 4; ++r) {
      int b = kg*4 + r;
      psum[0][b][lr] = x0[r]; psum[1][b][lr] = x1[r]; psum[2][b][lr] = x2[r];
      psum[3][b][lr] = h0[r]; psum[4][b][lr] = h1[r]; psum[5][b][lr] = h2[r];
    }
  }
  __syncthreads();
  if (wv == 0) {
    float bi0 = bi ? bi[j] : 0.f, bi1 = bi ? bi[1024 + j] : 0.f, bi2 = bi ? bi[2048 + j] : 0.f;
    float bh0 = bh[j], bh1 = bh[1024 + j], bh2 = bh[2048 + j];
    #pragma unroll
    for (int r = 0; r < 4; ++r) {
      int b = kg*4 + r;
      float gxa0 = gxadd ? gxadd[(long)b*G3D + j]        : 0.f;
      float gxa1 = gxadd ? gxadd[(long)b*G3D + 1024 + j] : 0.f;
      float gxa2 = gxadd ? gxadd[(long)b*G3D + 2048 + j] : 0.f;
      float gx0 = x0[r] + psum[0][b][lr] + gxa0 + bi0;
      float gx1 = x1[r] + psum[1][b][lr] + gxa1 + bi1;
      float gx2 = x2[r] + psum[2][b][lr] + gxa2 + bi2;
      float gh0 = h0[r] + psum[3][b][lr] + bh0;
      float gh1 = h1[r] + psum[4][b][lr] + bh1;
      float gh2 = h2[r] + psum[5][b][lr] + bh2;
      float rr = fsig(gx0 + gh0);
      float zz = fsig(gx1 + gh1);
      float nn = ftanh(gx2 + rr*gh2);
      float hp = hprev[b*1024 + j];
      float hn = (1.f - zz)*nn + zz*hp;
      hout[b*1024 + j] = hn;
      houtb[b*1024 + j] = f2bf(hn);
      if (catb) catb[(long)b*2048 + j] = f2bf(hn);
    }
  }
}

// ---------------- fused decoder attention v3: 64 blocks, per-b 4-slot barrier ----------------
__global__ __launch_bounds__(256) void k_dec_attn3(
    const ushort* __restrict__ h1b, const ushort* __restrict__ memdb,
    float* __restrict__ cov, float* __restrict__ coveS, float* __restrict__ covacc,
    float* __restrict__ scb,
    ushort* __restrict__ ctxn, ushort* __restrict__ catb,
    int* __restrict__ slots, int epoch)
{
  const int bid = blockIdx.x, tid = threadIdx.x;
  const int b = bid >> 2, q = bid & 3;
  const int wv = tid >> 6, lane = tid & 63;
  __shared__ float at[TSN];
  __shared__ float red[256];
  __shared__ float psD[4][64][4];
  float hr[16];
  {
    bf16x8 hv0 = *(const bf16x8*)&h1b[b*1024 + lane*16];
    bf16x8 hv1 = *(const bf16x8*)&h1b[b*1024 + lane*16 + 8];
    #pragma unroll
    for (int e = 0; e < 8; ++e) { hr[e] = bf2f((ushort)hv0[e]); hr[8+e] = bf2f((ushort)hv1[e]); }
  }
  #pragma unroll 2
  for (int i = 0; i < 25; ++i) {
    int t = q*100 + wv*25 + i;
    const ushort* row = memdb + ((long)b*TSN + t)*1024 + lane*16;
    bf16x8 r0 = *(const bf16x8*)row;
    bf16x8 r1 = *(const bf16x8*)(row + 8);
    float p = 0.f;
    #pragma unroll
    for (int e = 0; e < 8; ++e) p += hr[e]*bf2f((ushort)r0[e]) + hr[8+e]*bf2f((ushort)r1[e]);
    #pragma unroll
    for (int off = 32; off; off >>= 1) p += __shfl_xor(p, off);
    if (lane == 0) agat_st((unsigned*)&scb[b*TSN + t], __float_as_uint(p));
  }
  asm volatile("s_waitcnt vmcnt(0)" ::: "memory");
  __syncthreads();
  if (tid == 0) agat_st((unsigned*)(slots + bid*32), (unsigned)epoch);
  if (tid < 4) {
    while ((int)agat_ld((const unsigned*)(slots + (b*4 + tid)*32)) < epoch)
      __builtin_amdgcn_s_sleep(1);
  }
  __syncthreads();
  {
    bool t1v = tid < 144;
    float sc0 = __uint_as_float(agat_ld((const unsigned*)&scb[b*TSN + tid]));
    float sc1 = t1v ? __uint_as_float(agat_ld((const unsigned*)&scb[b*TSN + 256 + tid])) : 0.f;
    float co0 = cov[b*TSN + tid];
    float co1 = t1v ? cov[b*TSN + 256 + tid] : 0.f;
    float ce0 = sc0*(1.f - co0);
    float ce1 = t1v ? sc1*(1.f - co1) : -INFINITY;
    red[tid] = fmaxf(ce0, ce1); __syncthreads();
    for (int o = 128; o; o >>= 1) { if (tid < o) red[tid] = fmaxf(red[tid], red[tid+o]); __syncthreads(); }
    float m = red[0]; __syncthreads();
    float ex0 = __expf(ce0 - m), ex1 = t1v ? __expf(ce1 - m) : 0.f;
    red[tid] = ex0 + ex1; __syncthreads();
    for (int o = 128; o; o >>= 1) { if (tid < o) red[tid] += red[tid+o]; __syncthreads(); }
    float inv = 1.f/red[0]; __syncthreads();
    float a0 = ex0*inv, a1 = ex1*inv;
    at[tid] = a0;
    if (t1v) at[256 + tid] = a1;
    if (q == 0) {
      coveS[b*TSN + tid] = ce0;
      if (t1v) coveS[b*TSN + 256 + tid] = ce1;
      cov[b*TSN + tid] = co0 + a0;
      if (t1v) cov[b*TSN + 256 + tid] = co1 + a1;
      red[tid] = fminf(a0, co0) + (t1v ? fminf(a1, co1) : 0.f);
      __syncthreads();
      for (int o = 128; o; o >>= 1) { if (tid < o) red[tid] += red[tid+o]; __syncthreads(); }
      if (tid == 0) atomicAdd(covacc, red[0]);
    }
  }
  __syncthreads();
  {
    float acc4[4] = {};
    const int d0 = q*256 + lane*4;
    const unsigned* base = (const unsigned*)memdb + (((long)b*TSN*1024 + d0) >> 1);
    for (int t = wv*100; t < wv*100 + 100; ++t) {
      float a = at[t];
      const unsigned* p = base + (long)t*512;
      unsigned dv0 = p[0], dv1 = p[1];
      acc4[0] += a*bf2f((ushort)(dv0 & 0xffffu));
      acc4[1] += a*bf2f((ushort)(dv0 >> 16));
      acc4[2] += a*bf2f((ushort)(dv1 & 0xffffu));
      acc4[3] += a*bf2f((ushort)(dv1 >> 16));
    }
    #pragma unroll
    for (int e = 0; e < 4; ++e) psD[wv][lane][e] = acc4[e];
    __syncthreads();
    if (wv == 0) {
      float c[4];
      #pragma unroll
      for (int e = 0; e < 4; ++e)
        c[e] = psD[0][lane][e] + psD[1][lane][e] + psD[2][lane][e] + psD[3][lane][e];
      unsigned w0 = (unsigned)f2bf(c[0]) | ((unsigned)f2bf(c[1]) << 16);
      unsigned w1 = (unsigned)f2bf(c[2]) | ((unsigned)f2bf(c[3]) << 16);
      unsigned* cp = (unsigned*)ctxn + ((b*1024 + d0) >> 1);
      cp[0] = w0; cp[1] = w1;
      unsigned* kp = (unsigned*)catb + (((long)b*2048 + 1024 + d0) >> 1);
      kp[0] = w0; kp[1] = w1;
    }
  }
}

// ---------------- hid = tanh(cat @ pW1^T + pb1): 64 blocks x 128 ----------------
__global__ __launch_bounds__(128) void k_hid(
    const ushort* __restrict__ catb, const ushort* __restrict__ W,
    const float* __restrict__ pb1, ushort* __restrict__ hidb)
{
  const int wv = threadIdx.x >> 6;
  const int lane = threadIdx.x & 63;
  const int lr = lane & 15, kg = lane >> 4;
  const int n = blockIdx.x*16 + lr;
  const int kb = wv*1024;
  __shared__ float ps[16][16];
  f32x4 acc = {};
  const ushort* ap = catb + lr*2048 + kb + kg*8;
  const ushort* wp = W + ((long)n << 11) + kb + kg*8;
  #pragma unroll 8
  for (int k0 = 0; k0 < 1024; k0 += 32)
    acc = __builtin_amdgcn_mfma_f32_16x16x32_bf16(*(const bf16x8*)(ap + k0), *(const bf16x8*)(wp + k0), acc, 0, 0, 0);
  if (wv == 1) {
    #pragma unroll
    for (int r = 0; r < 4; ++r) ps[kg*4 + r][lr] = acc[r];
  }
  __syncthreads();
  if (wv == 0) {
    float bv = pb1[n];
    #pragma unroll
    for (int r = 0; r < 4; ++r) {
      int b = kg*4 + r;
      hidb[b*1024 + n] = f2bf(ftanh(acc[r] + ps[b][lr] + bv));
    }
  }
}

// ---------------- batched logits ----------------
__global__ __launch_bounds__(256) void k_logits_all(
    const ushort* __restrict__ hidAll,
    const ushort* __restrict__ pW2b,
    const float* __restrict__ pb2,
    float* __restrict__ outp)
{
  const int wave = threadIdx.x >> 6, lane = threadIdx.x & 63;
  const int lr = lane & 15, kg = lane >> 4;
  const int n0 = blockIdx.x*256 + wave*64;
  const int m0 = blockIdx.y*128;
  f32x4 acc[8][4] = {};
  for (int k0 = 0; k0 < 1024; k0 += 32) {
    bf16x8 bfr[4];
    #pragma unroll
    for (int nt = 0; nt < 4; ++nt)
      bfr[nt] = *(const bf16x8*)&pW2b[(long)(n0 + nt*16 + lr)*1024 + k0 + kg*8];
    #pragma unroll
    for (int mt = 0; mt < 8; ++mt) {
      bf16x8 af = *(const bf16x8*)&hidAll[(long)(m0 + mt*16 + lr)*1024 + k0 + kg*8];
      #pragma unroll
      for (int nt = 0; nt < 4; ++nt)
        acc[mt][nt] = __builtin_amdgcn_mfma_f32_16x16x32_bf16(af, bfr[nt], acc[mt][nt], 0, 0, 0);
    }
  }
  #pragma unroll
  for (int nt = 0; nt < 4; ++nt) {
    int v = n0 + nt*16 + lr;
    if (v >= NEXT) continue;
    float pb = (v < NV) ? pb2[v] : 0.f;
    #pragma unroll
    for (int mt = 0; mt < 8; ++mt) {
      #pragma unroll
      for (int r = 0; r < 4; ++r) {
        int m = m0 + mt*16 + kg*4 + r;
        int s = m >> 4, b = m & 15;
        float e = (v < NV) ? (acc[mt][nt][r] + pb) : 0.f;
        if (e == 0.f) e = NEG_INF;
        outp[((long)b*NTT + s)*NEXT + v] = e;
      }
    }
  }
}

// ---------------- copy-scatter compose ----------------
__device__ __forceinline__ float dec_f(unsigned e) {
  return (e & 0x80000000u) ? __uint_as_float(e ^ 0x80000000u) : __uint_as_float(~e);
}
__global__ __launch_bounds__(512) void k_compose_all(
    const int* __restrict__ ids, const float* __restrict__ coveAll,
    unsigned* __restrict__ ubuf, float* __restrict__ outp)
{
  int b = blockIdx.x, tid = threadIdx.x;
  int v = 0;
  if (tid < TSN) v = ids[b*TSN + tid];
  unsigned* up = ubuf + (long)b*NEXT;
  for (int s = 0; s < NTT; ++s) {
    if (tid < TSN) {
      float ce = coveAll[((long)s*NB + b)*TSN + tid];
      unsigned bb = __float_as_uint(ce);
      unsigned enc = (bb & 0x80000000u) ? ~bb : (bb | 0x80000000u);
      atomicMax(&up[v], enc);
    }
    __syncthreads();
    if (tid < TSN) {
      unsigned u = __hip_atomic_load(&up[v], __ATOMIC_RELAXED, __HIP_MEMORY_SCOPE_AGENT);
      float o = dec_f(u);
      long oi = ((long)b*NTT + s)*NEXT + v;
      float e = outp[oi];
      if (e == NEG_INF) e = 0.f;
      float lg = e + o;
      if (lg == 0.f) lg = NEG_INF;
      outp[oi] = lg;
    }
    __syncthreads();
    if (tid < TSN)
      __hip_atomic_store(&up[v], 0u, __ATOMIC_RELAXED, __HIP_MEMORY_SCOPE_AGENT);
    __syncthreads();
  }
}

// ---------------- final coverage-loss scalar ----------------
__global__ void k_covout(const float* __restrict__ covacc, float* __restrict__ outp)
{
  outp[(long)NB*NTT*NEXT] = covacc[0] * (1.0f/(NB*NTT));
}

// ==================== host ====================
extern "C" void kernel_launch(void* const* d_in, const int* in_sizes, int n_in,
                              void* d_out, int out_size, void* d_ws, size_t ws_size,
                              hipStream_t stream) {
  (void)in_sizes; (void)n_in; (void)out_size; (void)ws_size;
  const float* enc_emb = (const float*)d_in[0];
  const float* ans_emb = (const float*)d_in[1];
  const float* dec_emb = (const float*)d_in[2];
  const float* eWi0 = (const float*)d_in[3];
  const float* eWh0 = (const float*)d_in[4];
  const float* ebi0 = (const float*)d_in[5];
  const float* ebh0 = (const float*)d_in[6];
  const float* eWi1 = (const float*)d_in[7];
  const float* eWh1 = (const float*)d_in[8];
  const float* ebi1 = (const float*)d_in[9];
  const float* ebh1 = (const float*)d_in[10];
  const float* trans_W = (const float*)d_in[11];
  const float* trans_b = (const float*)d_in[12];
  const float* upd_W = (const float*)d_in[13];
  const float* gate_W = (const float*)d_in[14];
  const float* dWi0 = (const float*)d_in[15];
  const float* dWh0 = (const float*)d_in[16];
  const float* dbi0 = (const float*)d_in[17];
  const float* dbh0 = (const float*)d_in[18];
  const float* dWi1 = (const float*)d_in[19];
  const float* dWh1 = (const float*)d_in[20];
  const float* dbi1 = (const float*)d_in[21];
  const float* dbh1 = (const float*)d_in[22];
  const float* dtrans_W = (const float*)d_in[23];
  const float* dtrans_b = (const float*)d_in[24];
  const float* pW1 = (const float*)d_in[25];
  const float* pb1 = (const float*)d_in[26];
  const float* pW2 = (const float*)d_in[27];
  const float* pb2 = (const float*)d_in[28];
  const int* input_s = (const int*)d_in[29];
  const int* ext_ids = (const int*)d_in[30];
  const int* input_q = (const int*)d_in[31];
  const int* input_a = (const int*)d_in[32];
  float* out = (float*)d_out;

  float* ws = (float*)d_ws;
  size_t off = 0;
  auto alloc = [&](size_t n) { float* p = ws + off; off += (n + 15) & ~(size_t)15; return p; };
  auto alloch = [&](size_t nh) { return (ushort*)alloc((nh + 1) / 2); };

  // --- small persistent ---
  ushort* hpp  = alloch(2ull*2*NB*HENC);
  int*   bar   = (int*)alloc(4096);
  float* covacc= alloc(4);
  float* cov   = alloc(NB*TSN);
  float* scb   = alloc(NB*TSN);
  unsigned* ubuf = (unsigned*)alloc((size_t)NB*NEXT);
  float* hfin0 = alloc(NB*HD2);
  float* hfin1 = alloc(NB*HD2);
  float* dh0   = alloc(2ull*NB*HD2);
  float* dh1   = alloc(2ull*NB*HD2);
  ushort* h0b  = alloch(2ull*NB*HD2);
  ushort* h1b  = alloch(2ull*NB*HD2);
  ushort* ctxbf= alloch(2ull*NB*HD2);
  ushort* catbf= alloch((size_t)NB*2048);
  ushort* hidAll = alloch((size_t)NTT*NB*HD2);
  float* coveAll = alloc((size_t)NTT*NB*TSN);

  // --- bf16 weights ---
  ushort* eWi0c   = alloch(2ull*G3E*384);
  ushort* eWi1c   = alloch(2ull*G3E*1024);
  ushort* Whb0    = alloch(2ull*G3E*HENC);
  ushort* Whb1    = alloch(2ull*G3E*HENC);
  ushort* transWb = alloch(1024ull*1024);
  ushort* fgWb    = alloch(2048ull*2048);
  ushort* dtransWb= alloch(1024ull*1024);
  ushort* dWi0e   = alloch(3072ull*320);
  ushort* dWi0c   = alloch(3072ull*1024);
  ushort* dWh0b   = alloch(3072ull*1024);
  ushort* dWi1b   = alloch(3072ull*1024);
  ushort* dWh1b   = alloch(3072ull*1024);
  ushort* pW1b    = alloch(1024ull*2048);

  // --- alias region: [GX(bf16) | X0c | Y0bf | pad] -> later ftgt_bf, then pW2b ---
  size_t regionStart = off;
  float*  GXr  = alloc(2ull*6400*G3E);
  ushort* GXbf = (ushort*)GXr;
  ushort* X0c  = alloch(6400ull*384);
  ushort* Y0bf = alloch(6400ull*1024);
  alloc(6400ull*HD2);
  ushort* ftgt_bf = (ushort*)(ws + regionStart);
  ushort* pW2b    = (ushort*)(ws + regionStart);
  ushort* outpTb  = (ushort*)(ws + regionStart + 26000000);

  // --- big buffers ---
  ushort* memsbf = alloch(6400ull*HD2);
  ushort* catE   = alloch(6400ull*2048);     // [6400][2048] = [enc_out | ctx]
  float*  energ  = alloc((size_t)NB*TSN*TSN);
  ushort* scoresb= alloch((size_t)NB*TSN*448);
  ushort* memd_bf= alloch(6400ull*HD2);
  ushort* encbf  = alloch(6400ull*HD2);
  ushort* embqb  = alloch(512ull*320);
  float*  embGX  = alloc(512ull*G3D);

  // ---------------- one-time casts ----------------
  k_embed_bf<<<9600, 256, 0, stream>>>(enc_emb, ans_emb, input_s, input_a, X0c);
  k_castw<<<4608, 256, 0, stream>>>(eWi0, eWi0c, 3072, 3072ull*384, 332, 384, 332, 0);
  {
    CJobs jobs;
    jobs.nj = 11;
    jobs.j[0]  = { (const float4*)eWi1,    eWi1c,               393216 };
    jobs.j[1]  = { (const float4*)eWh0,    Whb0,                196608 };
    jobs.j[2]  = { (const float4*)eWh1,    Whb1,                196608 };
    jobs.j[3]  = { (const float4*)trans_W, transWb,             131072 };
    jobs.j[4]  = { (const float4*)upd_W,   fgWb,                262144 };
    jobs.j[5]  = { (const float4*)gate_W,  fgWb + 1024ull*2048, 262144 };
    jobs.j[6]  = { (const float4*)dtrans_W, dtransWb,           131072 };
    jobs.j[7]  = { (const float4*)dWh0,    dWh0b,               393216 };
    jobs.j[8]  = { (const float4*)dWi1,    dWi1b,               393216 };
    jobs.j[9]  = { (const float4*)dWh1,    dWh1b,               393216 };
    jobs.j[10] = { (const float4*)pW1,     pW1b,                262144 };
    k_cast8_multi<<<2048, 256, 0, stream>>>(jobs);
  }
  k_castw<<<3840, 256, 0, stream>>>(dWi0, dWi0e, 3072, 3072ull*320, 300, 320, 1324, 0);
  k_castw<<<12288, 256, 0, stream>>>(dWi0, dWi0c, 3072, 3072ull*1024, 1024, 1024, 1324, 300);

  hipMemsetAsync(bar, 0, 16384, stream);

  // ---------------- encoder layer 0 ----------------
  k_mfma128<<<dim3(50,12,2), 256, 0, stream>>>(X0c, eWi0c, ebi0, GXbf,
      384, 384, 384, G3E, 0, (long)G3E*384, 6400ull*G3E, G3E);
  hipMemsetAsync(hpp, 0, 2ull*2*NB*HENC*2, stream);
  k_scan_mfma<<<121, 256, 0, stream>>>(GXbf, GXbf + 6400ull*G3E, Whb0, ebh0,
      Y0bf, 0, 1024, hfin0, hpp, bar);
  // ---------------- encoder layer 1 (writes catE lower half directly) ----------------
  k_mfma128<<<dim3(50,12,2), 256, 0, stream>>>(Y0bf, eWi1c, ebi1, GXbf,
      1024, 1024, 1024, G3E, 0, (long)G3E*1024, 6400ull*G3E, G3E);
  hipMemsetAsync(hpp, 0, 2ull*2*NB*HENC*2, stream);
  k_scan_mfma<<<121, 256, 0, stream>>>(GXbf, GXbf + 6400ull*G3E, Whb1, ebh1,
      catE, 1, 2048, hfin1, hpp, bar + 512);

  // ---------------- self/answer attention ----------------
  k_mfma128<<<dim3(50,8,1), 256, 0, stream>>>(catE, transWb, trans_b, memsbf,
      1024, 2048, 1024, 1024, 0, 0, 0, 0);
  k_mfma_nt<<<dim3(7,7,16), 256, 0, stream>>>(catE, memsbf, nullptr, energ, nullptr,
      TSN, TSN, 1024, 2048, 1024, TSN, (long)TSN*2048, (long)TSN*1024, (long)TSN*TSN, 0, 0, 0);
  k_softmax_bf<<<NB*TSN, 256, 0, stream>>>(energ, scoresb);
  k_transpose_hh<<<dim3(14,32,16), 256, 0, stream>>>(catE, outpTb, 2048);
  k_mfma_nt<<<dim3(7,16,16), 256, 0, stream>>>(scoresb, outpTb, nullptr, nullptr, catE + 1024,
      TSN, HD2, 448, 448, 448, 2048, (long)TSN*448, (long)HD2*448, (long)TSN*2048, 0, 0, 0);
  k_mfma128<<<dim3(50,16,1), 256, 0, stream>>>(catE, fgWb, nullptr, ftgt_bf,
      2048, 2048, 2048, 2048, 0, 0, 0, 0);
  k_ansatt2<<<64, 256, 0, stream>>>(memsbf, ftgt_bf, catE, input_a, encbf);
  // region dead after ansatt2: cast pW2 over it (vectorized) + zero pad rows
  k_cast8<<<25000, 256, 0, stream>>>((const float4*)pW2, pW2b, 6400000);
  hipMemsetAsync(pW2b + 50000l*1024, 0, 176l*1024*2, stream);
  k_mfma128<<<dim3(50,8,1), 256, 0, stream>>>(encbf, dtransWb, dtrans_b, memd_bf,
      1024, 1024, 1024, 1024, 0, 0, 0, 0);

  // ---------------- decoder precompute ----------------
  k_embq_bf<<<640, 256, 0, stream>>>(dec_emb, input_q, embqb);
  k_mfma_nt<<<dim3(8,48,1), 256, 0, stream>>>(embqb, dWi0e, dbi0, embGX, nullptr,
      NTT*NB, G3D, 320, 320, 320, G3D, 0, 0, 0, 0, 0, 0);

  hipMemsetAsync(cov, 0, (size_t)NB*TSN*4, stream);
  hipMemsetAsync(covacc, 0, 4, stream);
  hipMemsetAsync(ubuf, 0, (size_t)NB*NEXT*4, stream);
  hipMemsetAsync(ctxbf, 0, (size_t)NB*HD2*2, stream);
  hipMemcpyAsync(dh0, hfin0, (size_t)NB*HD2*4, hipMemcpyDeviceToDevice, stream);
  hipMemcpyAsync(dh1, hfin1, (size_t)NB*HD2*4, hipMemcpyDeviceToDevice, stream);
  k_cast<<<64, 256, 0, stream>>>(hfin0, h0b, 16384);
  k_cast<<<64, 256, 0, stream>>>(hfin1, h1b, 16384);

  // ---------------- decoder steps ----------------
  for (int s = 0; s < NTT; ++s) {
    int cur = s & 1, nxt = cur ^ 1;
    float* h0c = dh0 + (size_t)cur*NB*HD2;  float* h0n = dh0 + (size_t)nxt*NB*HD2;
    float* h1c = dh1 + (size_t)cur*NB*HD2;  float* h1n = dh1 + (size_t)nxt*NB*HD2;
    ushort* h0bc = h0b + (size_t)cur*NB*HD2; ushort* h0bn = h0b + (size_t)nxt*NB*HD2;
    ushort* h1bc = h1b + (size_t)cur*NB*HD2; ushort* h1bn = h1b + (size_t)nxt*NB*HD2;
    ushort* ctxc = ctxbf + (size_t)cur*NB*HD2; ushort* ctxn = ctxbf + (size_t)nxt*NB*HD2;

    k_gru_dec<<<64, 128, 0, stream>>>(ctxc, dWi0c, h0bc, dWh0b,
        embGX + (size_t)s*NB*G3D, nullptr, dbh0, h0c, h0n, h0bn, nullptr);
    k_gru_dec<<<64, 128, 0, stream>>>(h0bn, dWi1b, h1bc, dWh1b,
        nullptr, dbi1, dbh1, h1c, h1n, h1bn, catbf);
    k_dec_attn3<<<64, 256, 0, stream>>>(h1bn, memd_bf,
        cov, coveAll + (size_t)s*NB*TSN, covacc, scb, ctxn, catbf,
        bar + 1024, s + 1);
    k_hid<<<64, 128, 0, stream>>>(catbf, pW1b, pb1, hidAll + (size_t)s*NB*HD2);
  }
  // ---------------- batched logits + compose ----------------
  k_logits_all<<<dim3(196, 4), 256, 0, stream>>>(hidAll, pW2b, pb2, out);
  k_compose_all<<<NB, 512, 0, stream>>>(ext_ids, coveAll, ubuf, out);
  k_covout<<<1, 1, 0, stream>>>(covacc, out);
}